// Round 1
// baseline (2407.975 us; speedup 1.0000x reference)
//
#include <hip/hip_runtime.h>
#include <math.h>

// Sizes (fixed by the reference)
//  B=32 S=512 V=32000 D_IN=512 D_MODEL=2048 HEADS=8 HD=64
//  N_OUT=64 N_ACT=32 M=10 MH=64 T=20

__device__ __forceinline__ float sigf(float x) { return 1.0f / (1.0f + __expf(-x)); }
__device__ __forceinline__ float decf(float d) { return __expf(-fminf(fmaxf(d, 0.0f), 15.0f)); }

// ---------------------------------------------------------------------------
// K0: init trace (circular slots = initial m), act, aa/ba[0]=0, ao/bo[0], stats=0
// ---------------------------------------------------------------------------
__global__ __launch_bounds__(256) void k0_init(
    const float* __restrict__ st_tr, const float* __restrict__ st_ac,
    const int* __restrict__ iol, const int* __restrict__ ior,
    float* __restrict__ trace, float* __restrict__ act,
    float* __restrict__ aaB, float* __restrict__ baB,
    float* __restrict__ aoB, float* __restrict__ boB, float* __restrict__ stats)
{
    const int i = blockIdx.x * 256 + threadIdx.x;
    if (i < 655360) {
        const int n = i & 2047;
        const int m = (i >> 11) % 10;
        trace[i] = st_tr[n * 10 + m];          // trace[b][slot=m][n] = start_trace[n][m]
    } else if (i < 720896) {
        const int j = i - 655360;
        act[j] = st_ac[j & 2047];
    } else if (i < 721920) {
        aaB[i - 720896] = 0.0f;
    } else if (i < 722944) {
        baB[i - 721920] = 0.0f;
    } else if (i < 724992) {
        const int j = i - 722944;
        const int k = j & 63;
        aoB[j] = st_ac[iol[k]] * st_ac[ior[k]];  // alpha_o init (same for all b)
    } else if (i < 727040) {
        boB[i - 724992] = 1.0f;                  // beta_o init
    } else if (i < 727104) {
        stats[i - 727040] = 0.0f;
    }
}

// ---------------------------------------------------------------------------
// S1: kh/vh = gather(emb, tok) @ [Wpk;Wpv]^T + bias.  f32 tiled GEMM 128x128x16.
// C[r][c] = sum_k emb[tok[r]][k] * Win[512+c][k] + b_in[512+c], r<16384, c<1024
// ---------------------------------------------------------------------------
__global__ __launch_bounds__(256) void s1_kvproj(
    const int* __restrict__ tok, const float* __restrict__ emb,
    const float* __restrict__ Win, const float* __restrict__ b_in,
    float* __restrict__ kh, float* __restrict__ vh)
{
    __shared__ float As[16][132];
    __shared__ float Bs[16][132];
    const int tid = threadIdx.x;
    const int cb = blockIdx.x & 7;
    const int rb = blockIdx.x >> 3;
    const int r0 = rb * 128, c0 = cb * 128;
    const int ra0 = tid >> 2, kq = tid & 3;
    const int ra1 = ra0 + 64;
    const int t0 = tok[r0 + ra0];
    const int t1 = tok[r0 + ra1];
    const float* a0p = emb + (size_t)t0 * 512 + kq * 4;
    const float* a1p = emb + (size_t)t1 * 512 + kq * 4;
    const float* b0p = Win + (size_t)(512 + c0 + ra0) * 512 + kq * 4;
    const float* b1p = Win + (size_t)(512 + c0 + ra1) * 512 + kq * 4;
    const int tx = tid & 15, ty = tid >> 4;
    float acc[8][8];
#pragma unroll
    for (int i = 0; i < 8; ++i)
#pragma unroll
        for (int j = 0; j < 8; ++j) acc[i][j] = 0.0f;

    for (int kt = 0; kt < 512; kt += 16) {
        const float4 av0 = *(const float4*)(a0p + kt);
        const float4 av1 = *(const float4*)(a1p + kt);
        const float4 bv0 = *(const float4*)(b0p + kt);
        const float4 bv1 = *(const float4*)(b1p + kt);
        __syncthreads();
        As[kq*4+0][ra0] = av0.x; As[kq*4+1][ra0] = av0.y; As[kq*4+2][ra0] = av0.z; As[kq*4+3][ra0] = av0.w;
        As[kq*4+0][ra1] = av1.x; As[kq*4+1][ra1] = av1.y; As[kq*4+2][ra1] = av1.z; As[kq*4+3][ra1] = av1.w;
        Bs[kq*4+0][ra0] = bv0.x; Bs[kq*4+1][ra0] = bv0.y; Bs[kq*4+2][ra0] = bv0.z; Bs[kq*4+3][ra0] = bv0.w;
        Bs[kq*4+0][ra1] = bv1.x; Bs[kq*4+1][ra1] = bv1.y; Bs[kq*4+2][ra1] = bv1.z; Bs[kq*4+3][ra1] = bv1.w;
        __syncthreads();
#pragma unroll
        for (int kk = 0; kk < 16; ++kk) {
            const float4 af0 = *(const float4*)&As[kk][ty*4];
            const float4 af1 = *(const float4*)&As[kk][64 + ty*4];
            const float4 bf0 = *(const float4*)&Bs[kk][tx*4];
            const float4 bf1 = *(const float4*)&Bs[kk][64 + tx*4];
            const float a[8] = {af0.x, af0.y, af0.z, af0.w, af1.x, af1.y, af1.z, af1.w};
            const float bv[8] = {bf0.x, bf0.y, bf0.z, bf0.w, bf1.x, bf1.y, bf1.z, bf1.w};
#pragma unroll
            for (int i = 0; i < 8; ++i)
#pragma unroll
                for (int j = 0; j < 8; ++j) acc[i][j] = fmaf(a[i], bv[j], acc[i][j]);
        }
    }
    const float4 bb0 = *(const float4*)(b_in + 512 + c0 + tx*4);
    const float4 bb1 = *(const float4*)(b_in + 512 + c0 + 64 + tx*4);
    float* base; int ccol;
    if (c0 < 512) { base = kh; ccol = c0; } else { base = vh; ccol = c0 - 512; }
#pragma unroll
    for (int ih = 0; ih < 2; ++ih)
#pragma unroll
        for (int i = 0; i < 4; ++i) {
            const int gr = r0 + ih*64 + ty*4 + i;
            const int ai = ih*4 + i;
            float4 o0 = { acc[ai][0]+bb0.x, acc[ai][1]+bb0.y, acc[ai][2]+bb0.z, acc[ai][3]+bb0.w };
            float4 o1 = { acc[ai][4]+bb1.x, acc[ai][5]+bb1.y, acc[ai][6]+bb1.z, acc[ai][7]+bb1.w };
            *(float4*)(base + (size_t)gr*512 + ccol + tx*4) = o0;
            *(float4*)(base + (size_t)gr*512 + ccol + 64 + tx*4) = o1;
        }
}

// ---------------------------------------------------------------------------
// S2: Wfused[c][j] = sum_{k<512} Wsyn[c][k] * Wattn_o[k][j]   (4096 x 512)
// ---------------------------------------------------------------------------
__global__ __launch_bounds__(256) void s2_wfused(
    const float* __restrict__ Wsyn, const float* __restrict__ Wao,
    float* __restrict__ Wfused)
{
    __shared__ float As[16][132];
    __shared__ float Bs[16][132];
    const int tid = threadIdx.x;
    const int cb = blockIdx.x & 3;
    const int rb = blockIdx.x >> 2;
    const int r0 = rb * 128, c0 = cb * 128;
    const int ra0 = tid >> 2, kq = tid & 3;
    const int ra1 = ra0 + 64;
    const float* a0p = Wsyn + (size_t)(r0 + ra0) * 2560 + kq * 4;
    const float* a1p = Wsyn + (size_t)(r0 + ra1) * 2560 + kq * 4;
    const int bk0 = tid >> 5, bq0 = tid & 31;
    const int tx = tid & 15, ty = tid >> 4;
    float acc[8][8];
#pragma unroll
    for (int i = 0; i < 8; ++i)
#pragma unroll
        for (int j = 0; j < 8; ++j) acc[i][j] = 0.0f;

    for (int kt = 0; kt < 512; kt += 16) {
        const float4 av0 = *(const float4*)(a0p + kt);
        const float4 av1 = *(const float4*)(a1p + kt);
        const float4 bv0 = *(const float4*)(Wao + (size_t)(kt + bk0) * 512 + c0 + bq0*4);
        const float4 bv1 = *(const float4*)(Wao + (size_t)(kt + bk0 + 8) * 512 + c0 + bq0*4);
        __syncthreads();
        As[kq*4+0][ra0] = av0.x; As[kq*4+1][ra0] = av0.y; As[kq*4+2][ra0] = av0.z; As[kq*4+3][ra0] = av0.w;
        As[kq*4+0][ra1] = av1.x; As[kq*4+1][ra1] = av1.y; As[kq*4+2][ra1] = av1.z; As[kq*4+3][ra1] = av1.w;
        *(float4*)&Bs[bk0][bq0*4] = bv0;
        *(float4*)&Bs[bk0+8][bq0*4] = bv1;
        __syncthreads();
#pragma unroll
        for (int kk = 0; kk < 16; ++kk) {
            const float4 af0 = *(const float4*)&As[kk][ty*4];
            const float4 af1 = *(const float4*)&As[kk][64 + ty*4];
            const float4 bf0 = *(const float4*)&Bs[kk][tx*4];
            const float4 bf1 = *(const float4*)&Bs[kk][64 + tx*4];
            const float a[8] = {af0.x, af0.y, af0.z, af0.w, af1.x, af1.y, af1.z, af1.w};
            const float bv[8] = {bf0.x, bf0.y, bf0.z, bf0.w, bf1.x, bf1.y, bf1.z, bf1.w};
#pragma unroll
            for (int i = 0; i < 8; ++i)
#pragma unroll
                for (int j = 0; j < 8; ++j) acc[i][j] = fmaf(a[i], bv[j], acc[i][j]);
        }
    }
#pragma unroll
    for (int ih = 0; ih < 2; ++ih)
#pragma unroll
        for (int i = 0; i < 4; ++i) {
            const int gr = r0 + ih*64 + ty*4 + i;
            const int ai = ih*4 + i;
            float4 o0 = { acc[ai][0], acc[ai][1], acc[ai][2], acc[ai][3] };
            float4 o1 = { acc[ai][4], acc[ai][5], acc[ai][6], acc[ai][7] };
            *(float4*)(Wfused + (size_t)gr*512 + c0 + tx*4) = o0;
            *(float4*)(Wfused + (size_t)gr*512 + c0 + 64 + tx*4) = o1;
        }
}

// ---------------------------------------------------------------------------
// S3: bsyn2[c] = bsyn[c] + sum_{k<512} battn_o[k] * Wsyn[c][k]
// ---------------------------------------------------------------------------
__global__ __launch_bounds__(256) void s3_bias(
    const float* __restrict__ Wsyn, const float* __restrict__ battn,
    const float* __restrict__ bsyn, float* __restrict__ bsyn2)
{
    const int c = blockIdx.x * 256 + threadIdx.x;
    float s = bsyn[c];
    const float4* wr = (const float4*)(Wsyn + (size_t)c * 2560);
#pragma unroll 4
    for (int k4 = 0; k4 < 128; ++k4) {
        const float4 w = wr[k4];
        const float4 bb = *(const float4*)(battn + k4*4);
        s += w.x*bb.x + w.y*bb.y + w.z*bb.z + w.w*bb.w;
    }
    bsyn2[c] = s;
}

// ---------------------------------------------------------------------------
// K1: per (b,h) block: a/o EMA updates (parity dbuf), q, qh, scores (LDS-staged
// kh, pad-65), softmax, PV (coalesced direct) -> attnh[b][h*64+d]
// ---------------------------------------------------------------------------
__global__ __launch_bounds__(256) void k1_attn(
    const float* __restrict__ act, const float* __restrict__ decay_a,
    const float* __restrict__ decay_o, const int* __restrict__ ial,
    const int* __restrict__ iar, const int* __restrict__ iol,
    const int* __restrict__ ior, const float* __restrict__ Wq,
    const float* __restrict__ bq, const float* __restrict__ Win,
    const float* __restrict__ b_in, const float* __restrict__ kh,
    const float* __restrict__ vh, float* __restrict__ aaB,
    float* __restrict__ baB, float* __restrict__ aoB, float* __restrict__ boB,
    float* __restrict__ attnh, float* __restrict__ stats, const int u)
{
    __shared__ float sync_lds[32];
    __shared__ float q_lds[512];
    __shared__ float qh_lds[64];
    __shared__ float sc[512];
    __shared__ float red[256];
    __shared__ float pp[2][128];
    __shared__ float pv[4][64];
    __shared__ float khs[8320];   // 128 x 65 (reused as 64x65 qh scratch)
    const int tid = threadIdx.x;
    const int b = blockIdx.x >> 3, h = blockIdx.x & 7;

    if (tid < 32) {
        const int j = tid;
        const float ra = decf(decay_a[j]);
        const float pa = act[b*2048 + ial[j]] * act[b*2048 + iar[j]];
        const float aa = fmaf(ra, aaB[(u & 1)*1024 + b*32 + j], pa);
        const float ban = fmaf(ra, baB[(u & 1)*1024 + b*32 + j], 1.0f);
        if (h == 0) { aaB[((u+1)&1)*1024 + b*32 + j] = aa; baB[((u+1)&1)*1024 + b*32 + j] = ban; }
        sync_lds[j] = aa * rsqrtf(ban);
    } else if (tid >= 64 && tid < 128) {
        if (u > 0) {
            const int j = tid - 64;
            const float ro = decf(decay_o[j]);
            const float po = act[b*2048 + iol[j]] * act[b*2048 + ior[j]];
            const float ao = fmaf(ro, aoB[((u-1)&1)*2048 + b*64 + j], po);
            const float bo = fmaf(ro, boB[((u-1)&1)*2048 + b*64 + j], 1.0f);
            if (h == 0) { aoB[(u&1)*2048 + b*64 + j] = ao; boB[(u&1)*2048 + b*64 + j] = bo; }
        }
    } else if (tid >= 128 && tid < 192) {
        if (u > 0 && blockIdx.x == 0) stats[tid - 128] = 0.0f;   // zero LN stats for this tick
    }
    __syncthreads();
    // q[c] = bq[c] + Wq[c][:] . sync_a
    for (int c = tid; c < 512; c += 256) {
        float s = bq[c];
        const float4* wr = (const float4*)(Wq + c*32);
#pragma unroll
        for (int j4 = 0; j4 < 8; ++j4) {
            const float4 w = wr[j4];
            const float4 sv = *(const float4*)&sync_lds[j4*4];
            s += w.x*sv.x + w.y*sv.y + w.z*sv.z + w.w*sv.w;
        }
        q_lds[c] = s;
    }
    __syncthreads();
    // qh[d] = bpq[h*64+d] + Wpq[h*64+d][:] . q  (k-split partials via LDS)
    {
        const int kq = tid & 63, dg = tid >> 6;
        float q8[8];
        {
            const float4 qa = *(const float4*)&q_lds[kq*8];
            const float4 qb = *(const float4*)&q_lds[kq*8 + 4];
            q8[0]=qa.x; q8[1]=qa.y; q8[2]=qa.z; q8[3]=qa.w;
            q8[4]=qb.x; q8[5]=qb.y; q8[6]=qb.z; q8[7]=qb.w;
        }
        const float* wb2 = Win + (size_t)(h*64)*512 + kq*8;
#pragma unroll 4
        for (int dd = 0; dd < 16; ++dd) {
            const int d = dg*16 + dd;
            const float4 w0 = *(const float4*)(wb2 + (size_t)d*512);
            const float4 w1 = *(const float4*)(wb2 + (size_t)d*512 + 4);
            khs[d*65 + kq] = w0.x*q8[0] + w0.y*q8[1] + w0.z*q8[2] + w0.w*q8[3]
                           + w1.x*q8[4] + w1.y*q8[5] + w1.z*q8[6] + w1.w*q8[7];
        }
    }
    __syncthreads();
    if (tid < 64) {
        float s = b_in[h*64 + tid];
        const float* p = &khs[tid*65];
        for (int k2 = 0; k2 < 64; ++k2) s += p[k2];
        qh_lds[tid] = s;
    }
    __syncthreads();
    // scores in 4 chunks of 128 rows (stage kh coalesced -> pad-65 LDS)
    for (int ch = 0; ch < 4; ++ch) {
        const int s0 = ch * 128;
#pragma unroll
        for (int ps = 0; ps < 8; ++ps) {
            const int slot = tid + ps*256;
            const int row = slot >> 4, dq = slot & 15;
            const float4 v = *(const float4*)(kh + (size_t)(b*512 + s0 + row)*512 + h*64 + dq*4);
            float* dst = &khs[row*65 + dq*4];
            dst[0] = v.x; dst[1] = v.y; dst[2] = v.z; dst[3] = v.w;
        }
        __syncthreads();
        {
            const int sl = tid & 127, dh = tid >> 7;
            const float* kr = &khs[sl*65 + dh*32];
            const float* qr = &qh_lds[dh*32];
            float a2 = 0.0f;
#pragma unroll
            for (int d = 0; d < 32; ++d) a2 = fmaf(kr[d], qr[d], a2);
            pp[dh][sl] = a2;
        }
        __syncthreads();
        if (tid < 128) sc[s0 + tid] = (pp[0][tid] + pp[1][tid]) * 0.125f;
    }
    __syncthreads();
    // softmax over 512
    const float v0 = sc[tid], v1 = sc[tid + 256];
    red[tid] = fmaxf(v0, v1);
    __syncthreads();
    for (int off = 128; off > 0; off >>= 1) {
        if (tid < off) red[tid] = fmaxf(red[tid], red[tid + off]);
        __syncthreads();
    }
    const float mx = red[0];
    __syncthreads();
    const float e0 = __expf(v0 - mx), e1 = __expf(v1 - mx);
    sc[tid] = e0; sc[tid + 256] = e1;
    red[tid] = e0 + e1;
    __syncthreads();
    for (int off = 128; off > 0; off >>= 1) {
        if (tid < off) red[tid] += red[tid + off];
        __syncthreads();
    }
    const float inv = 1.0f / red[0];
    // PV: coalesced direct reads of vh (lanes = d)
    {
        const int l = tid & 63, w = tid >> 6;
        const float* vb = vh + (size_t)(b*512 + w*128)*512 + h*64 + l;
        float a3 = 0.0f;
        for (int si = 0; si < 128; ++si) a3 = fmaf(sc[w*128 + si], vb[(size_t)si*512], a3);
        pv[w][l] = a3;
    }
    __syncthreads();
    if (tid < 64)
        attnh[b*512 + h*64 + tid] = (pv[0][tid] + pv[1][tid] + pv[2][tid] + pv[3][tid]) * inv;
}

// ---------------------------------------------------------------------------
// K2b: h[b][c],h[b][2048+c] = attnh@Wfused^T-part + act@Wsyn[:,512:]^T-part + bsyn2
// -> GLU -> sg ; block-partial LN stats via atomics.
// block: 8 c-pairs x 32 b; 512 thr = (b, pg in 0..1 -> 4 pairs, ks in 0..7 k-split)
// ---------------------------------------------------------------------------
__global__ __launch_bounds__(512) void k2b_syn(
    const float* __restrict__ attnh, const float* __restrict__ act,
    const float* __restrict__ Wfused, const float* __restrict__ Wsyn,
    const float* __restrict__ bsyn2, float* __restrict__ sg, float* __restrict__ stats)
{
    __shared__ float pre[32][132];
    __shared__ float part[4224];   // 16 rows x (8 ks * 33 + b)
    const int tid = threadIdx.x;
    const int c0 = blockIdx.x * 8;
    const int b = tid & 31, pg = (tid >> 5) & 1, ks = tid >> 6;
    float acc_a[4] = {0,0,0,0}, acc_g[4] = {0,0,0,0};

    for (int ch = 0; ch < 20; ++ch) {
        const int kc = ch * 128;
        const bool ph0 = (kc < 512);
        {
            const float* srcb = ph0 ? attnh : act;
            const int ld = ph0 ? 512 : 2048;
            const int ko = ph0 ? kc : (kc - 512);
            const int sb1 = tid >> 5, kq1 = tid & 31;
            const int sb2 = (tid + 512) >> 5, kq2 = tid & 31;
            const float4 v1 = *(const float4*)(srcb + sb1*ld + ko + kq1*4);
            const float4 v2 = *(const float4*)(srcb + sb2*ld + ko + kq2*4);
            __syncthreads();
            *(float4*)&pre[sb1][kq1*4] = v1;
            *(float4*)&pre[sb2][kq2*4] = v2;
            __syncthreads();
        }
        const float* wb = ph0 ? Wfused : Wsyn;
        const int ldw = ph0 ? 512 : 2560;
#pragma unroll
        for (int i4 = 0; i4 < 4; ++i4) {
            const int kl = ks*16 + i4*4;
            const float4 p4 = *(const float4*)&pre[b][kl];
            const int kg = kc + kl;   // Wfused col (ph0) or Wsyn col (512..2559)
            const float* wr  = wb + (size_t)(c0 + pg*4) * ldw + kg;
            const float* wrg = wb + (size_t)(2048 + c0 + pg*4) * ldw + kg;
#pragma unroll
            for (int j = 0; j < 4; ++j) {
                const float4 wa  = *(const float4*)(wr  + (size_t)j*ldw);
                const float4 wg4 = *(const float4*)(wrg + (size_t)j*ldw);
                acc_a[j] += p4.x*wa.x  + p4.y*wa.y  + p4.z*wa.z  + p4.w*wa.w;
                acc_g[j] += p4.x*wg4.x + p4.y*wg4.y + p4.z*wg4.z + p4.w*wg4.w;
            }
        }
    }
    __syncthreads();
#pragma unroll
    for (int j = 0; j < 4; ++j) {
        const int p = pg*4 + j;
        part[(p*2+0)*264 + ks*33 + b] = acc_a[j];
        part[(p*2+1)*264 + ks*33 + b] = acc_g[j];
    }
    __syncthreads();
    float glu = 0.0f; int p8 = 0, bb = 0;
    if (tid < 256) {
        p8 = tid >> 5; bb = tid & 31;
        float va = 0.0f, vg = 0.0f;
#pragma unroll
        for (int k2 = 0; k2 < 8; ++k2) {
            va += part[(p8*2+0)*264 + k2*33 + bb];
            vg += part[(p8*2+1)*264 + k2*33 + bb];
        }
        va += bsyn2[c0 + p8];
        vg += bsyn2[2048 + c0 + p8];
        glu = va * sigf(vg);
        sg[bb*2048 + c0 + p8] = glu;
    }
    __syncthreads();
    if (tid < 256) {
        part[bb*9 + p8] = glu;
        part[288 + bb*9 + p8] = glu * glu;
    }
    __syncthreads();
    if (tid < 32) {
        float s1 = 0.0f, s2 = 0.0f;
#pragma unroll
        for (int p = 0; p < 8; ++p) { s1 += part[tid*9 + p]; s2 += part[288 + tid*9 + p]; }
        atomicAdd(&stats[tid*2],     s1);
        atomicAdd(&stats[tid*2 + 1], s2);
    }
}

// ---------------------------------------------------------------------------
// K3: LN (from stats) fused into trace staging, write trace slot u%10,
// per-neuron NLM (10->128 GLU-> 64 ->2), act = h2[0]*sig(h2[1]).
// block: 8 neurons x all 32 b; 256 thr = (nl in 0..7, hg in 0..31 -> 2 GLU pairs)
// ---------------------------------------------------------------------------
__global__ __launch_bounds__(256) void k3_nlm(
    const float* __restrict__ sg, const float* __restrict__ stats,
    const float* __restrict__ ln_g, const float* __restrict__ ln_b,
    const float* __restrict__ W1, const float* __restrict__ b1,
    const float* __restrict__ W2, const float* __restrict__ b2,
    float* __restrict__ trace, float* __restrict__ act, const int u)
{
    __shared__ float tr[256 * 12];   // [(b*8+nl)*12 + m], m padded 10->12
    __shared__ float pk[8320];       // 16 x 520 partial buffer (2 passes over hg)
    const int tid = threadIdx.x;
    const int n0 = blockIdx.x * 8;
    // --- stage trace (m=0..8 from circular buffer, m=9 = LN(sg)) ---
    {
        const int bb = tid >> 3, nl0 = tid & 7;
        const int n = n0 + nl0;
        float* trow = &tr[tid * 12];
#pragma unroll
        for (int m = 0; m < 9; ++m) {
            const int slot = (u + 1 + m) % 10;
            trow[m] = trace[(bb*10 + slot)*2048 + n];
        }
        const float mean = stats[bb*2] * (1.0f/2048.0f);
        const float var  = stats[bb*2+1] * (1.0f/2048.0f) - mean*mean;
        const float rstd = rsqrtf(var + 1e-5f);
        const float v9 = (sg[bb*2048 + n] - mean) * rstd * ln_g[n] + ln_b[n];
        trow[9] = v9;
        trace[(bb*10 + (u % 10))*2048 + n] = v9;
    }
    const int nl = tid & 7, hg = tid >> 3;
    const int n = n0 + nl;
    // --- per-thread weights: hh = {2hg,2hg+1, 64+2hg,64+2hg+1} ---
    float w1v[4][10], b1v[4], w2v[2][2];
#pragma unroll
    for (int r = 0; r < 4; ++r) {
        const int hh = (r < 2) ? (2*hg + r) : (64 + 2*hg + (r - 2));
        b1v[r] = b1[n*128 + hh];
#pragma unroll
        for (int m = 0; m < 10; ++m) w1v[r][m] = W1[(m*128 + hh)*2048 + n];
    }
#pragma unroll
    for (int r = 0; r < 2; ++r) {
        const int hq = 2*hg + r;
        w2v[r][0] = W2[(hq*2 + 0)*2048 + n];
        w2v[r][1] = W2[(hq*2 + 1)*2048 + n];
    }
    __syncthreads();
    // --- layer1 + GLU + layer2 partials for all 32 b ---
    float a0[32], a1[32];
#pragma unroll
    for (int bb = 0; bb < 32; ++bb) {
        const float* trow = &tr[(bb*8 + nl)*12];
        const float4 t0 = *(const float4*)trow;
        const float4 t1 = *(const float4*)(trow + 4);
        const float2 t2 = *(const float2*)(trow + 8);
        const float t[10] = {t0.x,t0.y,t0.z,t0.w,t1.x,t1.y,t1.z,t1.w,t2.x,t2.y};
        float hh4[4];
#pragma unroll
        for (int r = 0; r < 4; ++r) {
            float s = b1v[r];
#pragma unroll
            for (int m = 0; m < 10; ++m) s = fmaf(t[m], w1v[r][m], s);
            hh4[r] = s;
        }
        const float g0 = hh4[0] * sigf(hh4[2]);
        const float g1 = hh4[1] * sigf(hh4[3]);
        a0[bb] = g0*w2v[0][0] + g1*w2v[1][0];
        a1[bb] = g0*w2v[0][1] + g1*w2v[1][1];
    }
    // --- reduce over the 32 hg groups (2 passes to fit LDS) ---
    float rs0 = 0.0f, rs1 = 0.0f;
    const int rbb = tid >> 3, rnl = tid & 7;
#pragma unroll
    for (int pass = 0; pass < 2; ++pass) {
        __syncthreads();
        if ((hg >> 4) == pass) {
            const int hgm = hg & 15;
#pragma unroll
            for (int bb = 0; bb < 32; ++bb) {
                pk[hgm*520 + (bb*2 + 0)*8 + nl] = a0[bb];
                pk[hgm*520 + (bb*2 + 1)*8 + nl] = a1[bb];
            }
        }
        __syncthreads();
        for (int hgm = 0; hgm < 16; ++hgm) {
            rs0 += pk[hgm*520 + (rbb*2 + 0)*8 + rnl];
            rs1 += pk[hgm*520 + (rbb*2 + 1)*8 + rnl];
        }
    }
    const float h2a = rs0 + b2[(n0 + rnl)*2 + 0];
    const float h2b = rs1 + b2[(n0 + rnl)*2 + 1];
    act[rbb*2048 + n0 + rnl] = h2a * sigf(h2b);
}

// ---------------------------------------------------------------------------
// K4: final o-update (uses act_20), sync_o, ratings, cert, outputs
// ---------------------------------------------------------------------------
__global__ __launch_bounds__(256) void k4_final(
    const float* __restrict__ aoB, const float* __restrict__ boB,
    const float* __restrict__ act, const float* __restrict__ decay_o,
    const int* __restrict__ iol, const int* __restrict__ ior,
    const float* __restrict__ Wout, const float* __restrict__ bout,
    float* __restrict__ out)
{
    __shared__ float sl[2048];
    const int tid = threadIdx.x;
    for (int idx = tid; idx < 2048; idx += 256) {
        const int b = idx >> 6, j = idx & 63;
        const float ro = decf(decay_o[j]);
        const float po = act[b*2048 + iol[j]] * act[b*2048 + ior[j]];
        const float ao = fmaf(ro, aoB[2048 + b*64 + j], po);   // O[1] holds state after u=19
        const float bo = fmaf(ro, boB[2048 + b*64 + j], 1.0f);
        const float sv = ao * rsqrtf(bo);
        sl[idx] = sv;
        out[96 + idx] = sv;                      // sync_o
    }
    __syncthreads();
    if (tid < 32) {
        float p = bout[0];
        for (int j = 0; j < 64; ++j) p = fmaf(sl[tid*64 + j], Wout[j], p);
        out[tid] = sigf(p);                      // ratings
    } else if (tid < 96) {
        out[32 + (tid - 32)] = ((tid - 32) & 1) ? 1.0f : 0.0f;   // cert = [0,1]
    }
}

// ---------------------------------------------------------------------------
extern "C" void kernel_launch(void* const* d_in, const int* in_sizes, int n_in,
                              void* d_out, int out_size, void* d_ws, size_t ws_size,
                              hipStream_t stream)
{
    (void)in_sizes; (void)n_in; (void)out_size;
    const int*   tok   = (const int*)  d_in[0];
    const float* emb   = (const float*)d_in[1];
    const float* st_tr = (const float*)d_in[2];
    const float* st_ac = (const float*)d_in[3];
    const float* dec_a = (const float*)d_in[4];
    const float* dec_o = (const float*)d_in[5];
    const int*   ial   = (const int*)  d_in[6];
    const int*   iar   = (const int*)  d_in[7];
    const int*   iol   = (const int*)  d_in[8];
    const int*   ior   = (const int*)  d_in[9];
    const float* Wq    = (const float*)d_in[10];
    const float* bq    = (const float*)d_in[11];
    const float* Win   = (const float*)d_in[12];
    const float* b_in  = (const float*)d_in[13];
    const float* Wao   = (const float*)d_in[14];
    const float* bao   = (const float*)d_in[15];
    const float* Wsyn  = (const float*)d_in[16];
    const float* bsyn  = (const float*)d_in[17];
    const float* ln_g  = (const float*)d_in[18];
    const float* ln_b  = (const float*)d_in[19];
    const float* W1    = (const float*)d_in[20];
    const float* b1    = (const float*)d_in[21];
    const float* W2    = (const float*)d_in[22];
    const float* b2    = (const float*)d_in[23];
    const float* Wout  = (const float*)d_in[24];
    const float* bout  = (const float*)d_in[25];
    float* out = (float*)d_out;
    float* ws = (float*)d_ws;
    float* kh    = ws + 0;          // 16384*512
    float* vh    = ws + 8388608;    // 16384*512
    float* attnh = ws + 16777216;   // 32*512
    float* sg    = ws + 16793600;   // 32*2048
    float* stats = ws + 16859136;   // 32*2
    float* trace = ws + 16859200;   // 32*10*2048
    float* actb  = ws + 17514560;   // 32*2048
    float* aaB   = ws + 17580096;   // 2*32*32
    float* baB   = ws + 17582144;   // 2*32*32
    float* aoB   = ws + 17584192;   // 2*32*64
    float* boB   = ws + 17588288;   // 2*32*64
    float* Wfus  = ws + 17592384;   // 4096*512
    float* bs2   = ws + 19689536;   // 4096
    if (ws_size < (size_t)19693632 * 4) return;

    k0_init<<<dim3(2841), dim3(256), 0, stream>>>(st_tr, st_ac, iol, ior,
        trace, actb, aaB, baB, aoB, boB, stats);
    s1_kvproj<<<dim3(1024), dim3(256), 0, stream>>>(tok, emb, Win, b_in, kh, vh);
    s2_wfused<<<dim3(128), dim3(256), 0, stream>>>(Wsyn, Wao, Wfus);
    s3_bias<<<dim3(16), dim3(256), 0, stream>>>(Wsyn, bao, bsyn, bs2);
    for (int u = 0; u < 20; ++u) {
        k1_attn<<<dim3(256), dim3(256), 0, stream>>>(actb, dec_a, dec_o,
            ial, iar, iol, ior, Wq, bq, Win, b_in, kh, vh,
            aaB, baB, aoB, boB, attnh, stats, u);
        k2b_syn<<<dim3(256), dim3(512), 0, stream>>>(attnh, actb, Wfus, Wsyn,
            bs2, sg, stats);
        k3_nlm<<<dim3(256), dim3(256), 0, stream>>>(sg, stats, ln_g, ln_b,
            W1, b1, W2, b2, trace, actb, u);
    }
    k4_final<<<dim3(1), dim3(256), 0, stream>>>(aoB, boB, actb, dec_o,
        iol, ior, Wout, bout, out);
}

// Round 2
// 1925.519 us; speedup vs baseline: 1.2506x; 1.2506x over previous
//
#include <hip/hip_runtime.h>
#include <math.h>

// Sizes: B=32 S=512 V=32000 D_IN=512 D_MODEL=2048 HEADS=8 HD=64
//        N_OUT=64 N_ACT=32 M=10 MH=64 T=20

typedef __attribute__((ext_vector_type(8))) short short8v;
typedef __attribute__((ext_vector_type(4))) float f32x4;

__device__ __forceinline__ float sigf(float x) { return 1.0f / (1.0f + __expf(-x)); }
__device__ __forceinline__ float decf(float d) { return __expf(-fminf(fmaxf(d, 0.0f), 15.0f)); }
__device__ __forceinline__ unsigned short bfr(float x) {
    unsigned int u = __float_as_uint(x);
    u += 0x7FFFu + ((u >> 16) & 1u);
    return (unsigned short)(u >> 16);
}
__device__ __forceinline__ float bff(unsigned short u) {
    return __uint_as_float(((unsigned int)u) << 16);
}
__device__ __forceinline__ unsigned int bf2(float lo, float hi) {
    unsigned int ul = __float_as_uint(lo); ul += 0x7FFFu + ((ul >> 16) & 1u);
    unsigned int uh = __float_as_uint(hi); uh += 0x7FFFu + ((uh >> 16) & 1u);
    return (ul >> 16) | (uh & 0xFFFF0000u);
}
#define BLO(u) __uint_as_float((u) << 16)
#define BHI(u) __uint_as_float((u) & 0xFFFF0000u)
// LDS swizzle for 128B rows: XOR 16B-chunk index with low 3 row bits
__device__ __forceinline__ int SWZ(int byteoff) {
    return byteoff ^ (((byteoff >> 7) & 7) << 4);
}

// ---------------------------------------------------------------------------
// K0: init trace (circular slots), act, aa/ba, ao/bo, stats
// ---------------------------------------------------------------------------
__global__ __launch_bounds__(256) void k0_init(
    const float* __restrict__ st_tr, const float* __restrict__ st_ac,
    const int* __restrict__ iol, const int* __restrict__ ior,
    float* __restrict__ trace, float* __restrict__ act,
    float* __restrict__ aaB, float* __restrict__ baB,
    float* __restrict__ aoB, float* __restrict__ boB, float* __restrict__ stats)
{
    const int i = blockIdx.x * 256 + threadIdx.x;
    if (i < 655360) {
        const int n = i & 2047;
        const int m = (i >> 11) % 10;
        trace[i] = st_tr[n * 10 + m];
    } else if (i < 720896) {
        const int j = i - 655360;
        act[j] = st_ac[j & 2047];
    } else if (i < 721920) {
        aaB[i - 720896] = 0.0f;
    } else if (i < 722944) {
        baB[i - 721920] = 0.0f;
    } else if (i < 724992) {
        const int j = i - 722944;
        const int k = j & 63;
        aoB[j] = st_ac[iol[k]] * st_ac[ior[k]];
    } else if (i < 727040) {
        boB[i - 724992] = 1.0f;
    } else if (i < 727104) {
        stats[i - 727040] = 0.0f;
    }
}

// ---------------------------------------------------------------------------
// S1: MFMA bf16 GEMM:  C(16384x1024) = gather(emb,tok)(16384x512) @ WinKV^T
// outputs bf16 khb (cols 0..511) / vhb (cols 512..1023), bias added.
// 128x128 tile, BK=64, 256 thr (4 waves 2x2), 16x16x32 MFMA, XOR-swizzled LDS.
// ---------------------------------------------------------------------------
__global__ __launch_bounds__(256) void s1_kv_mfma(
    const int* __restrict__ tok, const float* __restrict__ emb,
    const float* __restrict__ Win, const float* __restrict__ b_in,
    unsigned short* __restrict__ khb, unsigned short* __restrict__ vhb)
{
    __shared__ alignas(16) unsigned short Al[128 * 64];
    __shared__ alignas(16) unsigned short Bl[128 * 64];
    const int tid = threadIdx.x;
    const int cb = blockIdx.x & 7;
    const int rb = blockIdx.x >> 3;
    const int r0 = rb * 128, c0 = cb * 128;
    // staging map: 8 rounds, flat = tid + 256*j -> row = flat>>4, kq4 = flat&15
    int tokrow[8];
#pragma unroll
    for (int j = 0; j < 8; ++j) tokrow[j] = tok[r0 + ((tid + 256 * j) >> 4)];

    const int wid = tid >> 6, lane = tid & 63;
    const int wm = (wid >> 1) * 64, wn = (wid & 1) * 64;
    const int fr = lane & 15;
    const int fkb = (lane >> 4) * 16;   // k-offset in bytes within 64B half-row
    f32x4 acc[4][4];
#pragma unroll
    for (int i = 0; i < 4; ++i)
#pragma unroll
        for (int j = 0; j < 4; ++j)
#pragma unroll
            for (int e = 0; e < 4; ++e) acc[i][j][e] = 0.0f;

    for (int kt = 0; kt < 512; kt += 64) {
        float4 av[8], bv[8];
#pragma unroll
        for (int j = 0; j < 8; ++j) {
            const int flat = tid + 256 * j;
            const int row = flat >> 4, kq4 = flat & 15;
            av[j] = *(const float4*)(emb + (size_t)tokrow[j] * 512 + kt + kq4 * 4);
            bv[j] = *(const float4*)(Win + (size_t)(512 + c0 + row) * 512 + kt + kq4 * 4);
        }
        __syncthreads();
#pragma unroll
        for (int j = 0; j < 8; ++j) {
            const int flat = tid + 256 * j;
            const int row = flat >> 4, kq4 = flat & 15;
            const int boff = row * 128 + kq4 * 8;
            uint2 pa = { bf2(av[j].x, av[j].y), bf2(av[j].z, av[j].w) };
            uint2 pb = { bf2(bv[j].x, bv[j].y), bf2(bv[j].z, bv[j].w) };
            *(uint2*)((char*)Al + SWZ(boff)) = pa;
            *(uint2*)((char*)Bl + SWZ(boff)) = pb;
        }
        __syncthreads();
#pragma unroll
        for (int ks = 0; ks < 2; ++ks) {
            short8v af[4], bfv[4];
#pragma unroll
            for (int i = 0; i < 4; ++i)
                af[i] = *(const short8v*)((const char*)Al + SWZ((wm + i * 16 + fr) * 128 + ks * 64 + fkb));
#pragma unroll
            for (int j = 0; j < 4; ++j)
                bfv[j] = *(const short8v*)((const char*)Bl + SWZ((wn + j * 16 + fr) * 128 + ks * 64 + fkb));
#pragma unroll
            for (int i = 0; i < 4; ++i)
#pragma unroll
                for (int j = 0; j < 4; ++j)
                    acc[i][j] = __builtin_amdgcn_mfma_f32_16x16x32_bf16(af[i], bfv[j], acc[i][j], 0, 0, 0);
        }
    }
    // epilogue: C[r][c] + bias -> bf16
    unsigned short* outbase = (c0 < 512) ? khb : vhb;
    const int ccol = (c0 < 512) ? c0 : (c0 - 512);
#pragma unroll
    for (int j = 0; j < 4; ++j) {
        const int n = wn + j * 16 + fr;
        const float bias = b_in[512 + c0 + n];
#pragma unroll
        for (int i = 0; i < 4; ++i) {
            const int mbase = wm + i * 16 + (lane >> 4) * 4;
#pragma unroll
            for (int rr = 0; rr < 4; ++rr) {
                const int gr = r0 + mbase + rr;
                outbase[(size_t)gr * 512 + ccol + n] = bfr(acc[i][j][rr] + bias);
            }
        }
    }
}

// ---------------------------------------------------------------------------
// S2: Wfusb[c][j] = bf16( sum_k Wsyn[c][k] * Wattn_o[k][j] )   (4096 x 512)
// ---------------------------------------------------------------------------
__global__ __launch_bounds__(256) void s2_wfused(
    const float* __restrict__ Wsyn, const float* __restrict__ Wao,
    unsigned short* __restrict__ Wfusb)
{
    __shared__ float As[16][132];
    __shared__ float Bs[16][132];
    const int tid = threadIdx.x;
    const int cb = blockIdx.x & 3;
    const int rb = blockIdx.x >> 2;
    const int r0 = rb * 128, c0 = cb * 128;
    const int ra0 = tid >> 2, kq = tid & 3;
    const int ra1 = ra0 + 64;
    const float* a0p = Wsyn + (size_t)(r0 + ra0) * 2560 + kq * 4;
    const float* a1p = Wsyn + (size_t)(r0 + ra1) * 2560 + kq * 4;
    const int bk0 = tid >> 5, bq0 = tid & 31;
    const int tx = tid & 15, ty = tid >> 4;
    float acc[8][8];
#pragma unroll
    for (int i = 0; i < 8; ++i)
#pragma unroll
        for (int j = 0; j < 8; ++j) acc[i][j] = 0.0f;

    for (int kt = 0; kt < 512; kt += 16) {
        const float4 av0 = *(const float4*)(a0p + kt);
        const float4 av1 = *(const float4*)(a1p + kt);
        const float4 bv0 = *(const float4*)(Wao + (size_t)(kt + bk0) * 512 + c0 + bq0*4);
        const float4 bv1 = *(const float4*)(Wao + (size_t)(kt + bk0 + 8) * 512 + c0 + bq0*4);
        __syncthreads();
        As[kq*4+0][ra0] = av0.x; As[kq*4+1][ra0] = av0.y; As[kq*4+2][ra0] = av0.z; As[kq*4+3][ra0] = av0.w;
        As[kq*4+0][ra1] = av1.x; As[kq*4+1][ra1] = av1.y; As[kq*4+2][ra1] = av1.z; As[kq*4+3][ra1] = av1.w;
        *(float4*)&Bs[bk0][bq0*4] = bv0;
        *(float4*)&Bs[bk0+8][bq0*4] = bv1;
        __syncthreads();
#pragma unroll
        for (int kk = 0; kk < 16; ++kk) {
            const float4 af0 = *(const float4*)&As[kk][ty*4];
            const float4 af1 = *(const float4*)&As[kk][64 + ty*4];
            const float4 bf0 = *(const float4*)&Bs[kk][tx*4];
            const float4 bf1 = *(const float4*)&Bs[kk][64 + tx*4];
            const float a[8] = {af0.x, af0.y, af0.z, af0.w, af1.x, af1.y, af1.z, af1.w};
            const float bv[8] = {bf0.x, bf0.y, bf0.z, bf0.w, bf1.x, bf1.y, bf1.z, bf1.w};
#pragma unroll
            for (int i = 0; i < 8; ++i)
#pragma unroll
                for (int j = 0; j < 8; ++j) acc[i][j] = fmaf(a[i], bv[j], acc[i][j]);
        }
    }
#pragma unroll
    for (int ih = 0; ih < 2; ++ih)
#pragma unroll
        for (int i = 0; i < 4; ++i) {
            const int gr = r0 + ih*64 + ty*4 + i;
            const int ai = ih*4 + i;
            uint2 o0 = { bf2(acc[ai][0], acc[ai][1]), bf2(acc[ai][2], acc[ai][3]) };
            uint2 o1 = { bf2(acc[ai][4], acc[ai][5]), bf2(acc[ai][6], acc[ai][7]) };
            *(uint2*)(Wfusb + (size_t)gr*512 + c0 + tx*4) = o0;
            *(uint2*)(Wfusb + (size_t)gr*512 + c0 + 64 + tx*4) = o1;
        }
}

// ---------------------------------------------------------------------------
// S3: bsyn2[c] = bsyn[c] + sum_k battn_o[k] * Wsyn[c][k]   (f32)
// ---------------------------------------------------------------------------
__global__ __launch_bounds__(256) void s3_bias(
    const float* __restrict__ Wsyn, const float* __restrict__ battn,
    const float* __restrict__ bsyn, float* __restrict__ bsyn2)
{
    const int c = blockIdx.x * 256 + threadIdx.x;
    float s = bsyn[c];
    const float4* wr = (const float4*)(Wsyn + (size_t)c * 2560);
#pragma unroll 4
    for (int k4 = 0; k4 < 128; ++k4) {
        const float4 w = wr[k4];
        const float4 bb = *(const float4*)(battn + k4*4);
        s += w.x*bb.x + w.y*bb.y + w.z*bb.z + w.w*bb.w;
    }
    bsyn2[c] = s;
}

// ---------------------------------------------------------------------------
// S4: Wsb = bf16(Wsyn[:, 512:2560])  (4096 x 2048)
// ---------------------------------------------------------------------------
__global__ __launch_bounds__(256) void s4_convsyn(
    const float* __restrict__ Wsyn, unsigned short* __restrict__ Wsb)
{
    const int idx = blockIdx.x * 256 + threadIdx.x;   // x4 elements
    const int row = (idx * 4) >> 11, col = (idx * 4) & 2047;
    const float4 v = *(const float4*)(Wsyn + (size_t)row * 2560 + 512 + col);
    uint2 o = { bf2(v.x, v.y), bf2(v.z, v.w) };
    *(uint2*)(Wsb + (size_t)row * 2048 + col) = o;
}

// ---------------------------------------------------------------------------
// S5: W1t[n][hh][16] = {W1[m][hh][n] m=0..9, b1[n][hh], 0...} bf16
//     W2t[n][hq][2]  = W2[hq][o][n] bf16
// ---------------------------------------------------------------------------
__global__ __launch_bounds__(256) void s5_convnlm(
    const float* __restrict__ W1, const float* __restrict__ b1,
    const float* __restrict__ W2,
    unsigned short* __restrict__ W1t, unsigned short* __restrict__ W2t)
{
    const int t = blockIdx.x * 256 + threadIdx.x;   // 2048*128
    const int n = t >> 7, hh = t & 127;
    unsigned short tmp[16];
#pragma unroll
    for (int m = 0; m < 10; ++m) tmp[m] = bfr(W1[(size_t)(m * 128 + hh) * 2048 + n]);
    tmp[10] = bfr(b1[n * 128 + hh]);
    tmp[11] = 0; tmp[12] = 0; tmp[13] = 0; tmp[14] = 0; tmp[15] = 0;
    uint4 lo = { (unsigned)tmp[0] | ((unsigned)tmp[1] << 16), (unsigned)tmp[2] | ((unsigned)tmp[3] << 16),
                 (unsigned)tmp[4] | ((unsigned)tmp[5] << 16), (unsigned)tmp[6] | ((unsigned)tmp[7] << 16) };
    uint4 hi = { (unsigned)tmp[8] | ((unsigned)tmp[9] << 16), (unsigned)tmp[10] | ((unsigned)tmp[11] << 16),
                 (unsigned)tmp[12] | ((unsigned)tmp[13] << 16), (unsigned)tmp[14] | ((unsigned)tmp[15] << 16) };
    *(uint4*)(W1t + (size_t)t * 16) = lo;
    *(uint4*)(W1t + (size_t)t * 16 + 8) = hi;
    if (hh < 64) {
        const unsigned short a = bfr(W2[(size_t)(hh * 2 + 0) * 2048 + n]);
        const unsigned short g = bfr(W2[(size_t)(hh * 2 + 1) * 2048 + n]);
        *(unsigned int*)(W2t + (size_t)(n * 64 + hh) * 2) = (unsigned)a | ((unsigned)g << 16);
    }
}

// ---------------------------------------------------------------------------
// K1: per (b,h): EMA updates, q, qh, scores (bf16 kh staged->pad-65 f32 LDS),
// softmax, PV (bf16 vh staged->LDS)
// ---------------------------------------------------------------------------
__global__ __launch_bounds__(256) void k1_attn(
    const float* __restrict__ act, const float* __restrict__ decay_a,
    const float* __restrict__ decay_o, const int* __restrict__ ial,
    const int* __restrict__ iar, const int* __restrict__ iol,
    const int* __restrict__ ior, const float* __restrict__ Wq,
    const float* __restrict__ bq, const float* __restrict__ Win,
    const float* __restrict__ b_in, const unsigned short* __restrict__ khb,
    const unsigned short* __restrict__ vhb, float* __restrict__ aaB,
    float* __restrict__ baB, float* __restrict__ aoB, float* __restrict__ boB,
    float* __restrict__ attnh, float* __restrict__ stats, const int u)
{
    __shared__ float sync_lds[32];
    __shared__ float q_lds[512];
    __shared__ float qh_lds[64];
    __shared__ float sc[512];
    __shared__ float red[256];
    __shared__ float pp[2][128];
    __shared__ float pvred[4][64];
    __shared__ float khs[8320];   // 128 x 65
    const int tid = threadIdx.x;
    const int b = blockIdx.x >> 3, h = blockIdx.x & 7;

    if (tid < 32) {
        const int j = tid;
        const float ra = decf(decay_a[j]);
        const float pa = act[b*2048 + ial[j]] * act[b*2048 + iar[j]];
        const float aa = fmaf(ra, aaB[(u & 1)*1024 + b*32 + j], pa);
        const float ban = fmaf(ra, baB[(u & 1)*1024 + b*32 + j], 1.0f);
        if (h == 0) { aaB[((u+1)&1)*1024 + b*32 + j] = aa; baB[((u+1)&1)*1024 + b*32 + j] = ban; }
        sync_lds[j] = aa * rsqrtf(ban);
    } else if (tid >= 64 && tid < 128) {
        if (u > 0) {
            const int j = tid - 64;
            const float ro = decf(decay_o[j]);
            const float po = act[b*2048 + iol[j]] * act[b*2048 + ior[j]];
            const float ao = fmaf(ro, aoB[((u-1)&1)*2048 + b*64 + j], po);
            const float bo = fmaf(ro, boB[((u-1)&1)*2048 + b*64 + j], 1.0f);
            if (h == 0) { aoB[(u&1)*2048 + b*64 + j] = ao; boB[(u&1)*2048 + b*64 + j] = bo; }
        }
    } else if (tid >= 128 && tid < 192) {
        if (u > 0 && blockIdx.x == 0) stats[tid - 128] = 0.0f;
    }
    __syncthreads();
    // q = Wq . sync_a + bq
    for (int c = tid; c < 512; c += 256) {
        float s = bq[c];
        const float4* wr = (const float4*)(Wq + c*32);
#pragma unroll
        for (int j4 = 0; j4 < 8; ++j4) {
            const float4 w = wr[j4];
            const float4 sv = *(const float4*)&sync_lds[j4*4];
            s += w.x*sv.x + w.y*sv.y + w.z*sv.z + w.w*sv.w;
        }
        q_lds[c] = s;
    }
    __syncthreads();
    // qh (k-split partials in khs scratch)
    {
        const int kq = tid & 63, dg = tid >> 6;
        float q8[8];
        {
            const float4 qa = *(const float4*)&q_lds[kq*8];
            const float4 qb = *(const float4*)&q_lds[kq*8 + 4];
            q8[0]=qa.x; q8[1]=qa.y; q8[2]=qa.z; q8[3]=qa.w;
            q8[4]=qb.x; q8[5]=qb.y; q8[6]=qb.z; q8[7]=qb.w;
        }
        const float* wb2 = Win + (size_t)(h*64)*512 + kq*8;
#pragma unroll 4
        for (int dd = 0; dd < 16; ++dd) {
            const int d = dg*16 + dd;
            const float4 w0 = *(const float4*)(wb2 + (size_t)d*512);
            const float4 w1 = *(const float4*)(wb2 + (size_t)d*512 + 4);
            khs[d*65 + kq] = w0.x*q8[0] + w0.y*q8[1] + w0.z*q8[2] + w0.w*q8[3]
                           + w1.x*q8[4] + w1.y*q8[5] + w1.z*q8[6] + w1.w*q8[7];
        }
    }
    __syncthreads();
    if (tid < 64) {
        float s = b_in[h*64 + tid];
        const float* p = &khs[tid*65];
        for (int k2 = 0; k2 < 64; ++k2) s += p[k2];
        qh_lds[tid] = s;
    }
    // scores in 4 chunks of 128 rows
    for (int ch = 0; ch < 4; ++ch) {
        const int s0 = ch * 128;
        uint4 stg[4];
#pragma unroll
        for (int ps = 0; ps < 4; ++ps) {
            const int slot = tid + ps*256;
            const int row = slot >> 3, dq = slot & 7;
            stg[ps] = *(const uint4*)(khb + (size_t)(b*512 + s0 + row)*512 + h*64 + dq*8);
        }
        __syncthreads();   // khs free (qh readers / prev chunk compute done)
#pragma unroll
        for (int ps = 0; ps < 4; ++ps) {
            const int slot = tid + ps*256;
            const int row = slot >> 3, dq = slot & 7;
            float* dst = &khs[row*65 + dq*8];
            dst[0] = BLO(stg[ps].x); dst[1] = BHI(stg[ps].x);
            dst[2] = BLO(stg[ps].y); dst[3] = BHI(stg[ps].y);
            dst[4] = BLO(stg[ps].z); dst[5] = BHI(stg[ps].z);
            dst[6] = BLO(stg[ps].w); dst[7] = BHI(stg[ps].w);
        }
        __syncthreads();
        {
            const int sl = tid & 127, dh = tid >> 7;
            const float* kr = &khs[sl*65 + dh*32];
            const float* qr = &qh_lds[dh*32];
            float a2 = 0.0f;
#pragma unroll
            for (int d = 0; d < 32; ++d) a2 = fmaf(kr[d], qr[d], a2);
            pp[dh][sl] = a2;
        }
        __syncthreads();
        if (tid < 128) sc[s0 + tid] = (pp[0][tid] + pp[1][tid]) * 0.125f;
    }
    __syncthreads();
    // softmax over 512
    const float v0 = sc[tid], v1 = sc[tid + 256];
    red[tid] = fmaxf(v0, v1);
    __syncthreads();
    for (int off = 128; off > 0; off >>= 1) {
        if (tid < off) red[tid] = fmaxf(red[tid], red[tid + off]);
        __syncthreads();
    }
    const float mx = red[0];
    __syncthreads();
    const float e0 = __expf(v0 - mx), e1 = __expf(v1 - mx);
    sc[tid] = e0; sc[tid + 256] = e1;
    red[tid] = e0 + e1;
    __syncthreads();
    for (int off = 128; off > 0; off >>= 1) {
        if (tid < off) red[tid] += red[tid + off];
        __syncthreads();
    }
    const float inv = 1.0f / red[0];
    // PV via LDS-staged vh chunks
    float a3 = 0.0f;
    const int l = tid & 63, w = tid >> 6;
    for (int ch = 0; ch < 4; ++ch) {
        const int s0 = ch * 128;
        uint4 stg[4];
#pragma unroll
        for (int ps = 0; ps < 4; ++ps) {
            const int slot = tid + ps*256;
            const int row = slot >> 3, dq = slot & 7;
            stg[ps] = *(const uint4*)(vhb + (size_t)(b*512 + s0 + row)*512 + h*64 + dq*8);
        }
        __syncthreads();
#pragma unroll
        for (int ps = 0; ps < 4; ++ps) {
            const int slot = tid + ps*256;
            const int row = slot >> 3, dq = slot & 7;
            float* dst = &khs[row*65 + dq*8];
            dst[0] = BLO(stg[ps].x); dst[1] = BHI(stg[ps].x);
            dst[2] = BLO(stg[ps].y); dst[3] = BHI(stg[ps].y);
            dst[4] = BLO(stg[ps].z); dst[5] = BHI(stg[ps].z);
            dst[6] = BLO(stg[ps].w); dst[7] = BHI(stg[ps].w);
        }
        __syncthreads();
#pragma unroll
        for (int si = 0; si < 32; ++si)
            a3 = fmaf(sc[s0 + w*32 + si], khs[(w*32 + si)*65 + l], a3);
    }
    pvred[w][l] = a3;
    __syncthreads();
    if (tid < 64)
        attnh[b*512 + h*64 + tid] = (pvred[0][tid] + pvred[1][tid] + pvred[2][tid] + pvred[3][tid]) * inv;
}

// ---------------------------------------------------------------------------
// K2b: synapse GEMM (bf16 weights) -> GLU -> sg; LN stats via atomics
// ---------------------------------------------------------------------------
__global__ __launch_bounds__(512) void k2b_syn(
    const float* __restrict__ attnh, const float* __restrict__ act,
    const unsigned short* __restrict__ Wfusb, const unsigned short* __restrict__ Wsb,
    const float* __restrict__ bsyn2, float* __restrict__ sg, float* __restrict__ stats)
{
    __shared__ float pre[32][132];
    __shared__ float part[4224];
    const int tid = threadIdx.x;
    const int c0 = blockIdx.x * 8;
    const int b = tid & 31, pg = (tid >> 5) & 1, ks = tid >> 6;
    float acc_a[4] = {0,0,0,0}, acc_g[4] = {0,0,0,0};

    for (int ch = 0; ch < 20; ++ch) {
        const int kc = ch * 128;
        const bool ph0 = (kc < 512);
        {
            const float* srcb = ph0 ? attnh : act;
            const int ld = ph0 ? 512 : 2048;
            const int ko = ph0 ? kc : (kc - 512);
            const int sb1 = tid >> 5, kq1 = tid & 31;
            const int sb2 = (tid + 512) >> 5;
            const float4 v1 = *(const float4*)(srcb + sb1*ld + ko + kq1*4);
            const float4 v2 = *(const float4*)(srcb + sb2*ld + ko + kq1*4);
            __syncthreads();
            *(float4*)&pre[sb1][kq1*4] = v1;
            *(float4*)&pre[sb2][kq1*4] = v2;
            __syncthreads();
        }
        const unsigned short* wb = ph0 ? Wfusb : Wsb;
        const int ldw = ph0 ? 512 : 2048;
        const int kg = ph0 ? kc : (kc - 512);
#pragma unroll
        for (int i8 = 0; i8 < 2; ++i8) {
            const int kl = ks*16 + i8*8;
            const float4 pa4 = *(const float4*)&pre[b][kl];
            const float4 pb4 = *(const float4*)&pre[b][kl + 4];
            const int col = kg + kl;
            const unsigned short* wr  = wb + (size_t)(c0 + pg*4) * ldw + col;
            const unsigned short* wrg = wb + (size_t)(2048 + c0 + pg*4) * ldw + col;
#pragma unroll
            for (int j = 0; j < 4; ++j) {
                const uint4 wa = *(const uint4*)(wr  + (size_t)j*ldw);
                const uint4 wg = *(const uint4*)(wrg + (size_t)j*ldw);
                acc_a[j] += pa4.x*BLO(wa.x) + pa4.y*BHI(wa.x) + pa4.z*BLO(wa.y) + pa4.w*BHI(wa.y)
                          + pb4.x*BLO(wa.z) + pb4.y*BHI(wa.z) + pb4.z*BLO(wa.w) + pb4.w*BHI(wa.w);
                acc_g[j] += pa4.x*BLO(wg.x) + pa4.y*BHI(wg.x) + pa4.z*BLO(wg.y) + pa4.w*BHI(wg.y)
                          + pb4.x*BLO(wg.z) + pb4.y*BHI(wg.z) + pb4.z*BLO(wg.w) + pb4.w*BHI(wg.w);
            }
        }
    }
    __syncthreads();
#pragma unroll
    for (int j = 0; j < 4; ++j) {
        const int p = pg*4 + j;
        part[(p*2+0)*264 + ks*33 + b] = acc_a[j];
        part[(p*2+1)*264 + ks*33 + b] = acc_g[j];
    }
    __syncthreads();
    float glu = 0.0f; int p8 = 0, bb = 0;
    if (tid < 256) {
        p8 = tid >> 5; bb = tid & 31;
        float va = 0.0f, vg = 0.0f;
#pragma unroll
        for (int k2 = 0; k2 < 8; ++k2) {
            va += part[(p8*2+0)*264 + k2*33 + bb];
            vg += part[(p8*2+1)*264 + k2*33 + bb];
        }
        va += bsyn2[c0 + p8];
        vg += bsyn2[2048 + c0 + p8];
        glu = va * sigf(vg);
        sg[bb*2048 + c0 + p8] = glu;
    }
    __syncthreads();
    if (tid < 256) {
        part[bb*9 + p8] = glu;
        part[288 + bb*9 + p8] = glu * glu;
    }
    __syncthreads();
    if (tid < 32) {
        float s1 = 0.0f, s2 = 0.0f;
#pragma unroll
        for (int p = 0; p < 8; ++p) { s1 += part[tid*9 + p]; s2 += part[288 + tid*9 + p]; }
        atomicAdd(&stats[tid*2],     s1);
        atomicAdd(&stats[tid*2 + 1], s2);
    }
}

// ---------------------------------------------------------------------------
// K3: LN fused into trace staging, per-neuron NLM (bf16 W1t/W2t), act update
// ---------------------------------------------------------------------------
__global__ __launch_bounds__(256) void k3_nlm(
    const float* __restrict__ sg, const float* __restrict__ stats,
    const float* __restrict__ ln_g, const float* __restrict__ ln_b,
    const unsigned short* __restrict__ W1t, const unsigned short* __restrict__ W2t,
    const float* __restrict__ b2,
    float* __restrict__ trace, float* __restrict__ act, const int u)
{
    __shared__ float tr[256 * 12];
    __shared__ float pk[8320];
    const int tid = threadIdx.x;
    const int n0 = blockIdx.x * 8;
    {
        const int bb = tid >> 3, nl0 = tid & 7;
        const int n = n0 + nl0;
        float* trow = &tr[tid * 12];
#pragma unroll
        for (int m = 0; m < 9; ++m) {
            const int slot = (u + 1 + m) % 10;
            trow[m] = trace[(bb*10 + slot)*2048 + n];
        }
        const float mean = stats[bb*2] * (1.0f/2048.0f);
        const float var  = stats[bb*2+1] * (1.0f/2048.0f) - mean*mean;
        const float rstd = rsqrtf(var + 1e-5f);
        const float v9 = (sg[bb*2048 + n] - mean) * rstd * ln_g[n] + ln_b[n];
        trow[9] = v9;
        trace[(bb*10 + (u % 10))*2048 + n] = v9;
    }
    const int nl = tid & 7, hg = tid >> 3;
    const int n = n0 + nl;
    float w1v[4][10], b1v[4], w2v[2][2];
    const unsigned short* w1p = W1t + (size_t)(n * 128) * 16;
#pragma unroll
    for (int r = 0; r < 4; ++r) {
        const int hh = (r < 2) ? (2*hg + r) : (64 + 2*hg + (r - 2));
        const uint4 qa = *(const uint4*)(w1p + hh*16);
        const uint4 qb = *(const uint4*)(w1p + hh*16 + 8);
        w1v[r][0] = BLO(qa.x); w1v[r][1] = BHI(qa.x);
        w1v[r][2] = BLO(qa.y); w1v[r][3] = BHI(qa.y);
        w1v[r][4] = BLO(qa.z); w1v[r][5] = BHI(qa.z);
        w1v[r][6] = BLO(qa.w); w1v[r][7] = BHI(qa.w);
        w1v[r][8] = BLO(qb.x); w1v[r][9] = BHI(qb.x);
        b1v[r]    = BLO(qb.y);
    }
    {
        const uint2 q2 = *(const uint2*)(W2t + (size_t)(n * 64 + 2*hg) * 2);
        w2v[0][0] = BLO(q2.x); w2v[0][1] = BHI(q2.x);
        w2v[1][0] = BLO(q2.y); w2v[1][1] = BHI(q2.y);
    }
    __syncthreads();
    float a0[32], a1[32];
#pragma unroll
    for (int bb = 0; bb < 32; ++bb) {
        const float* trow = &tr[(bb*8 + nl)*12];
        const float4 t0 = *(const float4*)trow;
        const float4 t1 = *(const float4*)(trow + 4);
        const float2 t2 = *(const float2*)(trow + 8);
        const float t[10] = {t0.x,t0.y,t0.z,t0.w,t1.x,t1.y,t1.z,t1.w,t2.x,t2.y};
        float hh4[4];
#pragma unroll
        for (int r = 0; r < 4; ++r) {
            float s = b1v[r];
#pragma unroll
            for (int m = 0; m < 10; ++m) s = fmaf(t[m], w1v[r][m], s);
            hh4[r] = s;
        }
        const float g0 = hh4[0] * sigf(hh4[2]);
        const float g1 = hh4[1] * sigf(hh4[3]);
        a0[bb] = g0*w2v[0][0] + g1*w2v[1][0];
        a1[bb] = g0*w2v[0][1] + g1*w2v[1][1];
    }
    float rs0 = 0.0f, rs1 = 0.0f;
    const int rbb = tid >> 3, rnl = tid & 7;
#pragma unroll
    for (int pass = 0; pass < 2; ++pass) {
        __syncthreads();
        if ((hg >> 4) == pass) {
            const int hgm = hg & 15;
#pragma unroll
            for (int bb = 0; bb < 32; ++bb) {
                pk[hgm*520 + (bb*2 + 0)*8 + nl] = a0[bb];
                pk[hgm*520 + (bb*2 + 1)*8 + nl] = a1[bb];
            }
        }
        __syncthreads();
        for (int hgm = 0; hgm < 16; ++hgm) {
            rs0 += pk[hgm*520 + (rbb*2 + 0)*8 + rnl];
            rs1 += pk[hgm*520 + (rbb*2 + 1)*8 + rnl];
        }
    }
    const float h2a = rs0 + b2[(n0 + rnl)*2 + 0];
    const float h2b = rs1 + b2[(n0 + rnl)*2 + 1];
    act[rbb*2048 + n0 + rnl] = h2a * sigf(h2b);
}

// ---------------------------------------------------------------------------
// K4: final o-update, sync_o, ratings, cert
// ---------------------------------------------------------------------------
__global__ __launch_bounds__(256) void k4_final(
    const float* __restrict__ aoB, const float* __restrict__ boB,
    const float* __restrict__ act, const float* __restrict__ decay_o,
    const int* __restrict__ iol, const int* __restrict__ ior,
    const float* __restrict__ Wout, const float* __restrict__ bout,
    float* __restrict__ out)
{
    __shared__ float sl[2048];
    const int tid = threadIdx.x;
    for (int idx = tid; idx < 2048; idx += 256) {
        const int b = idx >> 6, j = idx & 63;
        const float ro = decf(decay_o[j]);
        const float po = act[b*2048 + iol[j]] * act[b*2048 + ior[j]];
        const float ao = fmaf(ro, aoB[2048 + b*64 + j], po);
        const float bo = fmaf(ro, boB[2048 + b*64 + j], 1.0f);
        const float sv = ao * rsqrtf(bo);
        sl[idx] = sv;
        out[96 + idx] = sv;
    }
    __syncthreads();
    if (tid < 32) {
        float p = bout[0];
        for (int j = 0; j < 64; ++j) p = fmaf(sl[tid*64 + j], Wout[j], p);
        out[tid] = sigf(p);
    } else if (tid < 96) {
        out[32 + (tid - 32)] = ((tid - 32) & 1) ? 1.0f : 0.0f;
    }
}

// ---------------------------------------------------------------------------
extern "C" void kernel_launch(void* const* d_in, const int* in_sizes, int n_in,
                              void* d_out, int out_size, void* d_ws, size_t ws_size,
                              hipStream_t stream)
{
    (void)in_sizes; (void)n_in; (void)out_size;
    const int*   tok   = (const int*)  d_in[0];
    const float* emb   = (const float*)d_in[1];
    const float* st_tr = (const float*)d_in[2];
    const float* st_ac = (const float*)d_in[3];
    const float* dec_a = (const float*)d_in[4];
    const float* dec_o = (const float*)d_in[5];
    const int*   ial   = (const int*)  d_in[6];
    const int*   iar   = (const int*)  d_in[7];
    const int*   iol   = (const int*)  d_in[8];
    const int*   ior   = (const int*)  d_in[9];
    const float* Wq    = (const float*)d_in[10];
    const float* bq    = (const float*)d_in[11];
    const float* Win   = (const float*)d_in[12];
    const float* b_in  = (const float*)d_in[13];
    const float* Wao   = (const float*)d_in[14];
    const float* bao   = (const float*)d_in[15];
    const float* Wsyn  = (const float*)d_in[16];
    const float* bsyn  = (const float*)d_in[17];
    const float* ln_g  = (const float*)d_in[18];
    const float* ln_b  = (const float*)d_in[19];
    const float* W1    = (const float*)d_in[20];
    const float* b1    = (const float*)d_in[21];
    const float* W2    = (const float*)d_in[22];
    const float* b2    = (const float*)d_in[23];
    const float* Wout  = (const float*)d_in[24];
    const float* bout  = (const float*)d_in[25];
    float* out = (float*)d_out;
    char* wsb = (char*)d_ws;
    if (ws_size < (size_t)66715904) return;
    unsigned short* khb   = (unsigned short*)(wsb + 0);          // 16 MB
    unsigned short* vhb   = (unsigned short*)(wsb + 16777216);   // 16 MB
    unsigned short* Wsb   = (unsigned short*)(wsb + 33554432);   // 16 MB
    unsigned short* W1t   = (unsigned short*)(wsb + 50331648);   // 8 MB
    unsigned short* Wfusb = (unsigned short*)(wsb + 58720256);   // 4 MB
    unsigned short* W2t   = (unsigned short*)(wsb + 62914560);   // 512 KB
    float* trace = (float*)(wsb + 63438848);   // 2.5 MB
    float* actb  = (float*)(wsb + 66060288);   // 256 KB
    float* sg    = (float*)(wsb + 66322432);   // 256 KB
    float* attnh = (float*)(wsb + 66584576);   // 64 KB
    float* aaB   = (float*)(wsb + 66650112);
    float* baB   = (float*)(wsb + 66658304);
    float* aoB   = (float*)(wsb + 66666496);
    float* boB   = (float*)(wsb + 66682880);
    float* bs2   = (float*)(wsb + 66699264);
    float* stats = (float*)(wsb + 66715648);

    k0_init<<<dim3(2841), dim3(256), 0, stream>>>(st_tr, st_ac, iol, ior,
        trace, actb, aaB, baB, aoB, boB, stats);
    s1_kv_mfma<<<dim3(1024), dim3(256), 0, stream>>>(tok, emb, Win, b_in, khb, vhb);
    s2_wfused<<<dim3(128), dim3(256), 0, stream>>>(Wsyn, Wao, Wfusb);
    s3_bias<<<dim3(16), dim3(256), 0, stream>>>(Wsyn, bao, bsyn, bs2);
    s4_convsyn<<<dim3(8192), dim3(256), 0, stream>>>(Wsyn, Wsb);
    s5_convnlm<<<dim3(1024), dim3(256), 0, stream>>>(W1, b1, W2, W1t, W2t);
    for (int u = 0; u < 20; ++u) {
        k1_attn<<<dim3(256), dim3(256), 0, stream>>>(actb, dec_a, dec_o,
            ial, iar, iol, ior, Wq, bq, Win, b_in, khb, vhb,
            aaB, baB, aoB, boB, attnh, stats, u);
        k2b_syn<<<dim3(256), dim3(512), 0, stream>>>(attnh, actb, Wfusb, Wsb,
            bs2, sg, stats);
        k3_nlm<<<dim3(256), dim3(256), 0, stream>>>(sg, stats, ln_g, ln_b,
            W1t, W2t, b2, trace, actb, u);
    }
    k4_final<<<dim3(1), dim3(256), 0, stream>>>(aoB, boB, actb, dec_o,
        iol, ior, Wout, bout, out);
}

// Round 3
// 1829.770 us; speedup vs baseline: 1.3160x; 1.0523x over previous
//
#include <hip/hip_runtime.h>
#include <math.h>

// Sizes: B=32 S=512 V=32000 D_IN=512 D_MODEL=2048 HEADS=8 HD=64
//        N_OUT=64 N_ACT=32 M=10 MH=64 T=20

typedef __attribute__((ext_vector_type(8))) short short8v;
typedef __attribute__((ext_vector_type(4))) float f32x4;

__device__ __forceinline__ float sigf(float x) { return 1.0f / (1.0f + __expf(-x)); }
__device__ __forceinline__ float decf(float d) { return __expf(-fminf(fmaxf(d, 0.0f), 15.0f)); }
__device__ __forceinline__ unsigned short bfr(float x) {
    unsigned int u = __float_as_uint(x);
    u += 0x7FFFu + ((u >> 16) & 1u);
    return (unsigned short)(u >> 16);
}
__device__ __forceinline__ float bff(unsigned short u) {
    return __uint_as_float(((unsigned int)u) << 16);
}
__device__ __forceinline__ unsigned int bf2(float lo, float hi) {
    unsigned int ul = __float_as_uint(lo); ul += 0x7FFFu + ((ul >> 16) & 1u);
    unsigned int uh = __float_as_uint(hi); uh += 0x7FFFu + ((uh >> 16) & 1u);
    return (ul >> 16) | (uh & 0xFFFF0000u);
}
#define BLO(u) __uint_as_float((u) << 16)
#define BHI(u) __uint_as_float((u) & 0xFFFF0000u)
// LDS swizzle for 128B rows: XOR 16B-chunk index with low 3 row bits
__device__ __forceinline__ int SWZ(int byteoff) {
    return byteoff ^ (((byteoff >> 7) & 7) << 4);
}

// ---------------------------------------------------------------------------
// K0: init trace (circular slots), act, aa/ba, ao/bo, stats
// ---------------------------------------------------------------------------
__global__ __launch_bounds__(256) void k0_init(
    const float* __restrict__ st_tr, const float* __restrict__ st_ac,
    const int* __restrict__ iol, const int* __restrict__ ior,
    float* __restrict__ trace, float* __restrict__ act,
    float* __restrict__ aaB, float* __restrict__ baB,
    float* __restrict__ aoB, float* __restrict__ boB, float* __restrict__ stats)
{
    const int i = blockIdx.x * 256 + threadIdx.x;
    if (i < 655360) {
        const int n = i & 2047;
        const int m = (i >> 11) % 10;
        trace[i] = st_tr[n * 10 + m];
    } else if (i < 720896) {
        const int j = i - 655360;
        act[j] = st_ac[j & 2047];
    } else if (i < 721920) {
        aaB[i - 720896] = 0.0f;
    } else if (i < 722944) {
        baB[i - 721920] = 0.0f;
    } else if (i < 724992) {
        const int j = i - 722944;
        const int k = j & 63;
        aoB[j] = st_ac[iol[k]] * st_ac[ior[k]];
    } else if (i < 727040) {
        boB[i - 724992] = 1.0f;
    } else if (i < 727104) {
        stats[i - 727040] = 0.0f;
    }
}

// ---------------------------------------------------------------------------
// S1: MFMA bf16 GEMM:  C(16384x1024) = gather(emb,tok)(16384x512) @ WinKV^T
// ---------------------------------------------------------------------------
__global__ __launch_bounds__(256) void s1_kv_mfma(
    const int* __restrict__ tok, const float* __restrict__ emb,
    const float* __restrict__ Win, const float* __restrict__ b_in,
    unsigned short* __restrict__ khb, unsigned short* __restrict__ vhb)
{
    __shared__ alignas(16) unsigned short Al[128 * 64];
    __shared__ alignas(16) unsigned short Bl[128 * 64];
    const int tid = threadIdx.x;
    const int cb = blockIdx.x & 7;
    const int rb = blockIdx.x >> 3;
    const int r0 = rb * 128, c0 = cb * 128;
    int tokrow[8];
#pragma unroll
    for (int j = 0; j < 8; ++j) tokrow[j] = tok[r0 + ((tid + 256 * j) >> 4)];

    const int wid = tid >> 6, lane = tid & 63;
    const int wm = (wid >> 1) * 64, wn = (wid & 1) * 64;
    const int fr = lane & 15;
    const int fkb = (lane >> 4) * 16;
    f32x4 acc[4][4];
#pragma unroll
    for (int i = 0; i < 4; ++i)
#pragma unroll
        for (int j = 0; j < 4; ++j)
#pragma unroll
            for (int e = 0; e < 4; ++e) acc[i][j][e] = 0.0f;

    for (int kt = 0; kt < 512; kt += 64) {
        float4 av[8], bv[8];
#pragma unroll
        for (int j = 0; j < 8; ++j) {
            const int flat = tid + 256 * j;
            const int row = flat >> 4, kq4 = flat & 15;
            av[j] = *(const float4*)(emb + (size_t)tokrow[j] * 512 + kt + kq4 * 4);
            bv[j] = *(const float4*)(Win + (size_t)(512 + c0 + row) * 512 + kt + kq4 * 4);
        }
        __syncthreads();
#pragma unroll
        for (int j = 0; j < 8; ++j) {
            const int flat = tid + 256 * j;
            const int row = flat >> 4, kq4 = flat & 15;
            const int boff = row * 128 + kq4 * 8;
            uint2 pa = { bf2(av[j].x, av[j].y), bf2(av[j].z, av[j].w) };
            uint2 pb = { bf2(bv[j].x, bv[j].y), bf2(bv[j].z, bv[j].w) };
            *(uint2*)((char*)Al + SWZ(boff)) = pa;
            *(uint2*)((char*)Bl + SWZ(boff)) = pb;
        }
        __syncthreads();
#pragma unroll
        for (int ks = 0; ks < 2; ++ks) {
            short8v af[4], bfv[4];
#pragma unroll
            for (int i = 0; i < 4; ++i)
                af[i] = *(const short8v*)((const char*)Al + SWZ((wm + i * 16 + fr) * 128 + ks * 64 + fkb));
#pragma unroll
            for (int j = 0; j < 4; ++j)
                bfv[j] = *(const short8v*)((const char*)Bl + SWZ((wn + j * 16 + fr) * 128 + ks * 64 + fkb));
#pragma unroll
            for (int i = 0; i < 4; ++i)
#pragma unroll
                for (int j = 0; j < 4; ++j)
                    acc[i][j] = __builtin_amdgcn_mfma_f32_16x16x32_bf16(af[i], bfv[j], acc[i][j], 0, 0, 0);
        }
    }
    unsigned short* outbase = (c0 < 512) ? khb : vhb;
    const int ccol = (c0 < 512) ? c0 : (c0 - 512);
#pragma unroll
    for (int j = 0; j < 4; ++j) {
        const int n = wn + j * 16 + fr;
        const float bias = b_in[512 + c0 + n];
#pragma unroll
        for (int i = 0; i < 4; ++i) {
            const int mbase = wm + i * 16 + (lane >> 4) * 4;
#pragma unroll
            for (int rr = 0; rr < 4; ++rr) {
                const int gr = r0 + mbase + rr;
                outbase[(size_t)gr * 512 + ccol + n] = bfr(acc[i][j][rr] + bias);
            }
        }
    }
}

// ---------------------------------------------------------------------------
// S2: Wfusb[c][j] = bf16( sum_k Wsyn[c][k] * Wattn_o[k][j] )   (4096 x 512)
// 64x64 tiles, grid 512 blocks (2/CU)
// ---------------------------------------------------------------------------
__global__ __launch_bounds__(256) void s2_wfused(
    const float* __restrict__ Wsyn, const float* __restrict__ Wao,
    unsigned short* __restrict__ Wfusb)
{
    __shared__ float As[16][68];
    __shared__ float Bs[16][68];
    const int tid = threadIdx.x;
    const int cb = blockIdx.x & 7;
    const int rb = blockIdx.x >> 3;
    const int r0 = rb * 64, c0 = cb * 64;
    const int ra = tid >> 2, kq = tid & 3;
    const int bk = tid >> 4, bq = tid & 15;
    const int tx = tid & 15, ty = tid >> 4;
    float acc[4][4];
#pragma unroll
    for (int i = 0; i < 4; ++i)
#pragma unroll
        for (int j = 0; j < 4; ++j) acc[i][j] = 0.0f;

    for (int kt = 0; kt < 512; kt += 16) {
        const float4 av = *(const float4*)(Wsyn + (size_t)(r0 + ra) * 2560 + kt + kq * 4);
        const float4 bv = *(const float4*)(Wao + (size_t)(kt + bk) * 512 + c0 + bq * 4);
        __syncthreads();
        As[kq*4+0][ra] = av.x; As[kq*4+1][ra] = av.y; As[kq*4+2][ra] = av.z; As[kq*4+3][ra] = av.w;
        *(float4*)&Bs[bk][bq*4] = bv;
        __syncthreads();
#pragma unroll
        for (int kk = 0; kk < 16; ++kk) {
            const float4 a4 = *(const float4*)&As[kk][ty*4];
            const float4 b4 = *(const float4*)&Bs[kk][tx*4];
            const float a[4] = {a4.x, a4.y, a4.z, a4.w};
            const float b[4] = {b4.x, b4.y, b4.z, b4.w};
#pragma unroll
            for (int i = 0; i < 4; ++i)
#pragma unroll
                for (int j = 0; j < 4; ++j) acc[i][j] = fmaf(a[i], b[j], acc[i][j]);
        }
    }
#pragma unroll
    for (int i = 0; i < 4; ++i) {
        const int gr = r0 + ty*4 + i;
        uint2 o = { bf2(acc[i][0], acc[i][1]), bf2(acc[i][2], acc[i][3]) };
        *(uint2*)(Wfusb + (size_t)gr*512 + c0 + tx*4) = o;
    }
}

// ---------------------------------------------------------------------------
// S3: bsyn2[c] = bsyn[c] + sum_k battn_o[k] * Wsyn[c][k]   (f32)
// ---------------------------------------------------------------------------
__global__ __launch_bounds__(256) void s3_bias(
    const float* __restrict__ Wsyn, const float* __restrict__ battn,
    const float* __restrict__ bsyn, float* __restrict__ bsyn2)
{
    const int c = blockIdx.x * 256 + threadIdx.x;
    float s = bsyn[c];
    const float4* wr = (const float4*)(Wsyn + (size_t)c * 2560);
#pragma unroll 4
    for (int k4 = 0; k4 < 128; ++k4) {
        const float4 w = wr[k4];
        const float4 bb = *(const float4*)(battn + k4*4);
        s += w.x*bb.x + w.y*bb.y + w.z*bb.z + w.w*bb.w;
    }
    bsyn2[c] = s;
}

// ---------------------------------------------------------------------------
// S4: Wsb = bf16(Wsyn[:, 512:2560])  (4096 x 2048)
// ---------------------------------------------------------------------------
__global__ __launch_bounds__(256) void s4_convsyn(
    const float* __restrict__ Wsyn, unsigned short* __restrict__ Wsb)
{
    const int idx = blockIdx.x * 256 + threadIdx.x;
    const int row = (idx * 4) >> 11, col = (idx * 4) & 2047;
    const float4 v = *(const float4*)(Wsyn + (size_t)row * 2560 + 512 + col);
    uint2 o = { bf2(v.x, v.y), bf2(v.z, v.w) };
    *(uint2*)(Wsb + (size_t)row * 2048 + col) = o;
}

// ---------------------------------------------------------------------------
// S5: NLM weight re-layout (coalesced for k3):
//   W1t[g][hh][nl][16] = {W1[m][hh][g*4+nl] m=0..9, b1, 0...}   (g = n>>2)
//   W2t[g][hq][nl][2]  = {W2[hq*2+0][n], W2[hq*2+1][n]}
// ---------------------------------------------------------------------------
__global__ __launch_bounds__(256) void s5_convnlm(
    const float* __restrict__ W1, const float* __restrict__ b1,
    const float* __restrict__ W2,
    unsigned short* __restrict__ W1t, unsigned short* __restrict__ W2t)
{
    const int t = blockIdx.x * 256 + threadIdx.x;   // 0..262143
    const int n = t & 2047, hh = t >> 11;
    unsigned short tmp[16];
#pragma unroll
    for (int m = 0; m < 10; ++m) tmp[m] = bfr(W1[(size_t)(m * 128 + hh) * 2048 + n]);
    tmp[10] = bfr(b1[n * 128 + hh]);
    tmp[11] = 0; tmp[12] = 0; tmp[13] = 0; tmp[14] = 0; tmp[15] = 0;
    uint4 lo = { (unsigned)tmp[0] | ((unsigned)tmp[1] << 16), (unsigned)tmp[2] | ((unsigned)tmp[3] << 16),
                 (unsigned)tmp[4] | ((unsigned)tmp[5] << 16), (unsigned)tmp[6] | ((unsigned)tmp[7] << 16) };
    uint4 hi = { (unsigned)tmp[8] | ((unsigned)tmp[9] << 16), (unsigned)tmp[10] | ((unsigned)tmp[11] << 16),
                 (unsigned)tmp[12] | ((unsigned)tmp[13] << 16), (unsigned)tmp[14] | ((unsigned)tmp[15] << 16) };
    const size_t o1 = ((size_t)((n >> 2) * 128 + hh) * 4 + (n & 3)) * 16;
    *(uint4*)(W1t + o1) = lo;
    *(uint4*)(W1t + o1 + 8) = hi;
    if (hh < 64) {
        const unsigned short a = bfr(W2[(size_t)(hh * 2 + 0) * 2048 + n]);
        const unsigned short g = bfr(W2[(size_t)(hh * 2 + 1) * 2048 + n]);
        *(unsigned int*)(W2t + ((size_t)((n >> 2) * 64 + hh) * 4 + (n & 3)) * 2) =
            (unsigned)a | ((unsigned)g << 16);
    }
}

// ---------------------------------------------------------------------------
// K1: per (b,h), 512 threads: EMA updates, q, qh, in-register scores,
// shfl softmax, coalesced PV
// ---------------------------------------------------------------------------
__global__ __launch_bounds__(512) void k1_attn(
    const float* __restrict__ act, const float* __restrict__ decay_a,
    const float* __restrict__ decay_o, const int* __restrict__ ial,
    const int* __restrict__ iar, const int* __restrict__ iol,
    const int* __restrict__ ior, const float* __restrict__ Wq,
    const float* __restrict__ bq, const float* __restrict__ Win,
    const float* __restrict__ b_in, const unsigned short* __restrict__ khb,
    const unsigned short* __restrict__ vhb, float* __restrict__ aaB,
    float* __restrict__ baB, float* __restrict__ aoB, float* __restrict__ boB,
    float* __restrict__ attnh, float* __restrict__ stats, const int u)
{
    __shared__ float sync_lds[32];
    __shared__ float q_lds[512];
    __shared__ float qh_lds[64];
    __shared__ float khs[64 * 65];   // qh k-split partials
    __shared__ float sc[512];        // exp(scores)
    __shared__ float red[16];
    __shared__ float pvred[8 * 64];
    const int tid = threadIdx.x;
    const int b = blockIdx.x >> 3, h = blockIdx.x & 7;

    if (tid < 32) {
        const int j = tid;
        const float ra = decf(decay_a[j]);
        const float pa = act[b*2048 + ial[j]] * act[b*2048 + iar[j]];
        const float aa = fmaf(ra, aaB[(u & 1)*1024 + b*32 + j], pa);
        const float ban = fmaf(ra, baB[(u & 1)*1024 + b*32 + j], 1.0f);
        if (h == 0) { aaB[((u+1)&1)*1024 + b*32 + j] = aa; baB[((u+1)&1)*1024 + b*32 + j] = ban; }
        sync_lds[j] = aa * rsqrtf(ban);
    } else if (tid >= 64 && tid < 128) {
        if (u > 0) {
            const int j = tid - 64;
            const float ro = decf(decay_o[j]);
            const float po = act[b*2048 + iol[j]] * act[b*2048 + ior[j]];
            const float ao = fmaf(ro, aoB[((u-1)&1)*2048 + b*64 + j], po);
            const float bo = fmaf(ro, boB[((u-1)&1)*2048 + b*64 + j], 1.0f);
            if (h == 0) { aoB[(u&1)*2048 + b*64 + j] = ao; boB[(u&1)*2048 + b*64 + j] = bo; }
        }
    } else if (tid >= 128 && tid < 192) {
        if (u > 0 && blockIdx.x == 0) stats[tid - 128] = 0.0f;
    }
    __syncthreads();
    // P1: q[c] for all 512 c (one per thread)
    {
        float s = bq[tid];
        const float4* wr = (const float4*)(Wq + tid*32);
#pragma unroll
        for (int j4 = 0; j4 < 8; ++j4) {
            const float4 w = wr[j4];
            const float4 sv = *(const float4*)&sync_lds[j4*4];
            s += w.x*sv.x + w.y*sv.y + w.z*sv.z + w.w*sv.w;
        }
        q_lds[tid] = s;
    }
    __syncthreads();
    // P2: qh[d] k-split partials
    {
        const int kq = tid & 63, dg = tid >> 6;
        float q8[8];
        {
            const float4 qa = *(const float4*)&q_lds[kq*8];
            const float4 qb = *(const float4*)&q_lds[kq*8 + 4];
            q8[0]=qa.x; q8[1]=qa.y; q8[2]=qa.z; q8[3]=qa.w;
            q8[4]=qb.x; q8[5]=qb.y; q8[6]=qb.z; q8[7]=qb.w;
        }
        const float* wb2 = Win + (size_t)(h*64)*512 + kq*8;
#pragma unroll
        for (int dd = 0; dd < 8; ++dd) {
            const int d = dg*8 + dd;
            const float4 w0 = *(const float4*)(wb2 + (size_t)d*512);
            const float4 w1 = *(const float4*)(wb2 + (size_t)d*512 + 4);
            khs[d*65 + kq] = w0.x*q8[0] + w0.y*q8[1] + w0.z*q8[2] + w0.w*q8[3]
                           + w1.x*q8[4] + w1.y*q8[5] + w1.z*q8[6] + w1.w*q8[7];
        }
    }
    __syncthreads();
    if (tid < 64) {
        float s = b_in[h*64 + tid];
        const float* p = &khs[tid*65];
        for (int k2 = 0; k2 < 64; ++k2) s += p[k2];
        qh_lds[tid] = s;
    }
    // P3: score row per thread (loads issued before qh sync)
    uint4 stg[8];
    {
        const unsigned short* krow = khb + (size_t)(b*512 + tid)*512 + h*64;
#pragma unroll
        for (int ps = 0; ps < 8; ++ps) stg[ps] = *(const uint4*)(krow + ps*8);
    }
    __syncthreads();
    float qv[64];
#pragma unroll
    for (int d4 = 0; d4 < 16; ++d4) {
        const float4 t4 = *(const float4*)&qh_lds[d4*4];
        qv[d4*4+0] = t4.x; qv[d4*4+1] = t4.y; qv[d4*4+2] = t4.z; qv[d4*4+3] = t4.w;
    }
    float sv = 0.0f;
#pragma unroll
    for (int ps = 0; ps < 8; ++ps) {
        sv = fmaf(BLO(stg[ps].x), qv[ps*8+0], sv); sv = fmaf(BHI(stg[ps].x), qv[ps*8+1], sv);
        sv = fmaf(BLO(stg[ps].y), qv[ps*8+2], sv); sv = fmaf(BHI(stg[ps].y), qv[ps*8+3], sv);
        sv = fmaf(BLO(stg[ps].z), qv[ps*8+4], sv); sv = fmaf(BHI(stg[ps].z), qv[ps*8+5], sv);
        sv = fmaf(BLO(stg[ps].w), qv[ps*8+6], sv); sv = fmaf(BHI(stg[ps].w), qv[ps*8+7], sv);
    }
    const float v = sv * 0.125f;
    // P4: softmax over 512 (wave shfl + 8-wave LDS combine)
    const int wid = tid >> 6;
    float m = v;
#pragma unroll
    for (int off = 32; off > 0; off >>= 1) m = fmaxf(m, __shfl_xor(m, off));
    if ((tid & 63) == 0) red[wid] = m;
    __syncthreads();
    float mx = red[0];
#pragma unroll
    for (int j = 1; j < 8; ++j) mx = fmaxf(mx, red[j]);
    const float e = __expf(v - mx);
    sc[tid] = e;
    float s = e;
#pragma unroll
    for (int off = 32; off > 0; off >>= 1) s += __shfl_xor(s, off);
    if ((tid & 63) == 0) red[8 + wid] = s;
    __syncthreads();
    float tot = red[8];
#pragma unroll
    for (int j = 1; j < 8; ++j) tot += red[8 + j];
    const float inv = 1.0f / tot;
    // P5: PV — thread (w,l): sum over 64 s of p[s]*vh[s][l]
    {
        const int l = tid & 63, w = tid >> 6;
        const unsigned short* vb = vhb + (size_t)(b*512 + w*64)*512 + h*64 + l;
        float a3 = 0.0f;
#pragma unroll 16
        for (int si = 0; si < 64; ++si)
            a3 = fmaf(sc[w*64 + si], bff(vb[(size_t)si*512]), a3);
        pvred[w*64 + l] = a3;
    }
    __syncthreads();
    if (tid < 64) {
        float a = 0.0f;
#pragma unroll
        for (int j = 0; j < 8; ++j) a += pvred[j*64 + tid];
        attnh[b*512 + h*64 + tid] = a * inv;
    }
}

// ---------------------------------------------------------------------------
// K2b: synapse GEMM (bf16 weights) -> GLU -> sg; LN stats via atomics.
// grid 512 (4 c-pairs each), 512 thr = (b = tid>>4, ks = tid&15)
// ---------------------------------------------------------------------------
__global__ __launch_bounds__(512) void k2b_syn(
    const float* __restrict__ attnh, const float* __restrict__ act,
    const unsigned short* __restrict__ Wfusb, const unsigned short* __restrict__ Wsb,
    const float* __restrict__ bsyn2, float* __restrict__ sg, float* __restrict__ stats)
{
    __shared__ float pre[32][132];
    __shared__ float part[8 * 544];
    const int tid = threadIdx.x;
    const int c0 = blockIdx.x * 4;
    const int ks = tid & 15, b = tid >> 4;
    float acc_a[4] = {0,0,0,0}, acc_g[4] = {0,0,0,0};

    for (int ch = 0; ch < 20; ++ch) {
        const int kc = ch * 128;
        const bool ph0 = (kc < 512);
        {
            const float* srcb = ph0 ? attnh : act;
            const int ld = ph0 ? 512 : 2048;
            const int ko = ph0 ? kc : (kc - 512);
            const int r1 = tid >> 5, q1 = tid & 31;
            const int r2 = (tid + 512) >> 5;
            const float4 v1 = *(const float4*)(srcb + r1*ld + ko + q1*4);
            const float4 v2 = *(const float4*)(srcb + r2*ld + ko + q1*4);
            __syncthreads();
            *(float4*)&pre[r1][q1*4] = v1;
            *(float4*)&pre[r2][q1*4] = v2;
            __syncthreads();
        }
        const unsigned short* wb = ph0 ? Wfusb : Wsb;
        const int ldw = ph0 ? 512 : 2048;
        const int kg = ph0 ? kc : (kc - 512);
        const int kl = ks * 8;
        const float4 pa4 = *(const float4*)&pre[b][kl];
        const float4 pb4 = *(const float4*)&pre[b][kl + 4];
        const int col = kg + kl;
#pragma unroll
        for (int j = 0; j < 4; ++j) {
            const uint4 wa = *(const uint4*)(wb + (size_t)(c0 + j) * ldw + col);
            const uint4 wg = *(const uint4*)(wb + (size_t)(2048 + c0 + j) * ldw + col);
            acc_a[j] += pa4.x*BLO(wa.x) + pa4.y*BHI(wa.x) + pa4.z*BLO(wa.y) + pa4.w*BHI(wa.y)
                      + pb4.x*BLO(wa.z) + pb4.y*BHI(wa.z) + pb4.z*BLO(wa.w) + pb4.w*BHI(wa.w);
            acc_g[j] += pa4.x*BLO(wg.x) + pa4.y*BHI(wg.x) + pa4.z*BLO(wg.y) + pa4.w*BHI(wg.y)
                      + pb4.x*BLO(wg.z) + pb4.y*BHI(wg.z) + pb4.z*BLO(wg.w) + pb4.w*BHI(wg.w);
        }
    }
    __syncthreads();
#pragma unroll
    for (int j = 0; j < 4; ++j) {
        part[(j*2+0)*544 + b*17 + ks] = acc_a[j];
        part[(j*2+1)*544 + b*17 + ks] = acc_g[j];
    }
    __syncthreads();
    float glu = 0.0f; int j8 = 0, bb = 0;
    if (tid < 128) {
        j8 = tid >> 5; bb = tid & 31;
        float va = 0.0f, vg = 0.0f;
#pragma unroll
        for (int k2 = 0; k2 < 16; ++k2) {
            va += part[(j8*2+0)*544 + bb*17 + k2];
            vg += part[(j8*2+1)*544 + bb*17 + k2];
        }
        va += bsyn2[c0 + j8];
        vg += bsyn2[2048 + c0 + j8];
        glu = va * sigf(vg);
        sg[bb*2048 + c0 + j8] = glu;
    }
    __syncthreads();
    if (tid < 128) {
        part[bb*4 + j8] = glu;
        part[160 + bb*4 + j8] = glu * glu;
    }
    __syncthreads();
    if (tid < 32) {
        float s1 = 0.0f, s2 = 0.0f;
#pragma unroll
        for (int j = 0; j < 4; ++j) { s1 += part[tid*4 + j]; s2 += part[160 + tid*4 + j]; }
        atomicAdd(&stats[tid*2],     s1);
        atomicAdd(&stats[tid*2 + 1], s2);
    }
}

// ---------------------------------------------------------------------------
// K3: LN fused into trace staging, per-neuron NLM, act update.
// grid 512 (4 neurons), 256 thr = (nl = tid&3, hg = tid>>2 in 0..63)
// ---------------------------------------------------------------------------
__global__ __launch_bounds__(256) void k3_nlm(
    const float* __restrict__ sg, const float* __restrict__ stats,
    const float* __restrict__ ln_g, const float* __restrict__ ln_b,
    const unsigned short* __restrict__ W1t, const unsigned short* __restrict__ W2t,
    const float* __restrict__ b2,
    float* __restrict__ trace, float* __restrict__ act, const int u)
{
    __shared__ float tr[128 * 12];
    __shared__ float pk[32 * 260];
    __shared__ float h2s[256];
    const int tid = threadIdx.x;
    const int n0 = blockIdx.x * 4;
    if (tid < 128) {
        const int bb = tid >> 2, nl0 = tid & 3;
        const int n = n0 + nl0;
        float* trow = &tr[tid * 12];
#pragma unroll
        for (int m = 0; m < 9; ++m) {
            const int slot = (u + 1 + m) % 10;
            trow[m] = trace[(bb*10 + slot)*2048 + n];
        }
        const float mean = stats[bb*2] * (1.0f/2048.0f);
        const float var  = stats[bb*2+1] * (1.0f/2048.0f) - mean*mean;
        const float rstd = rsqrtf(var + 1e-5f);
        const float v9 = (sg[bb*2048 + n] - mean) * rstd * ln_g[n] + ln_b[n];
        trow[9] = v9;
        trace[(bb*10 + (u % 10))*2048 + n] = v9;
    }
    const int nl = tid & 3, hg = tid >> 2;
    const int g = n0 >> 2;
    float w1a[10], w1g[10], b1a, b1g, w2v0, w2v1;
    {
        const unsigned short* pa = W1t + ((size_t)(g*128 + hg)*4 + nl)*16;
        const uint4 qa = *(const uint4*)pa;
        const uint4 qb = *(const uint4*)(pa + 8);
        w1a[0] = BLO(qa.x); w1a[1] = BHI(qa.x); w1a[2] = BLO(qa.y); w1a[3] = BHI(qa.y);
        w1a[4] = BLO(qa.z); w1a[5] = BHI(qa.z); w1a[6] = BLO(qa.w); w1a[7] = BHI(qa.w);
        w1a[8] = BLO(qb.x); w1a[9] = BHI(qb.x); b1a = BLO(qb.y);
        const unsigned short* pg = W1t + ((size_t)(g*128 + 64 + hg)*4 + nl)*16;
        const uint4 ra = *(const uint4*)pg;
        const uint4 rb = *(const uint4*)(pg + 8);
        w1g[0] = BLO(ra.x); w1g[1] = BHI(ra.x); w1g[2] = BLO(ra.y); w1g[3] = BHI(ra.y);
        w1g[4] = BLO(ra.z); w1g[5] = BHI(ra.z); w1g[6] = BLO(ra.w); w1g[7] = BHI(ra.w);
        w1g[8] = BLO(rb.x); w1g[9] = BHI(rb.x); b1g = BLO(rb.y);
        const unsigned int q2 = *(const unsigned int*)(W2t + ((size_t)(g*64 + hg)*4 + nl)*2);
        w2v0 = BLO(q2); w2v1 = BHI(q2);
    }
    __syncthreads();
    float a0[32], a1[32];
#pragma unroll
    for (int bb = 0; bb < 32; ++bb) {
        const float* trow = &tr[(bb*4 + nl)*12];
        const float4 t0 = *(const float4*)trow;
        const float4 t1 = *(const float4*)(trow + 4);
        const float2 t2 = *(const float2*)(trow + 8);
        const float t[10] = {t0.x,t0.y,t0.z,t0.w,t1.x,t1.y,t1.z,t1.w,t2.x,t2.y};
        float ha = b1a, hgv = b1g;
#pragma unroll
        for (int mm = 0; mm < 10; ++mm) {
            ha  = fmaf(t[mm], w1a[mm], ha);
            hgv = fmaf(t[mm], w1g[mm], hgv);
        }
        const float g0 = ha * sigf(hgv);
        a0[bb] = g0 * w2v0;
        a1[bb] = g0 * w2v1;
    }
    float rs = 0.0f;
#pragma unroll
    for (int pass = 0; pass < 2; ++pass) {
        __syncthreads();
        if ((hg >> 5) == pass) {
            const int hgm = hg & 31;
#pragma unroll
            for (int bb = 0; bb < 32; ++bb) {
                pk[hgm*260 + bb*8 + nl*2 + 0] = a0[bb];
                pk[hgm*260 + bb*8 + nl*2 + 1] = a1[bb];
            }
        }
        __syncthreads();
        for (int hgm = 0; hgm < 32; ++hgm) rs += pk[hgm*260 + tid];
    }
    const int onl = (tid >> 1) & 3, oo = tid & 1;
    rs += b2[(n0 + onl)*2 + oo];
    h2s[tid] = rs;
    __syncthreads();
    if (tid < 128) {
        const float h2a = h2s[tid*2], h2b = h2s[tid*2+1];
        act[(tid >> 2)*2048 + n0 + (tid & 3)] = h2a * sigf(h2b);
    }
}

// ---------------------------------------------------------------------------
// K4: final o-update, sync_o, ratings, cert
// ---------------------------------------------------------------------------
__global__ __launch_bounds__(256) void k4_final(
    const float* __restrict__ aoB, const float* __restrict__ boB,
    const float* __restrict__ act, const float* __restrict__ decay_o,
    const int* __restrict__ iol, const int* __restrict__ ior,
    const float* __restrict__ Wout, const float* __restrict__ bout,
    float* __restrict__ out)
{
    __shared__ float sl[2048];
    const int tid = threadIdx.x;
    for (int idx = tid; idx < 2048; idx += 256) {
        const int b = idx >> 6, j = idx & 63;
        const float ro = decf(decay_o[j]);
        const float po = act[b*2048 + iol[j]] * act[b*2048 + ior[j]];
        const float ao = fmaf(ro, aoB[2048 + b*64 + j], po);
        const float bo = fmaf(ro, boB[2048 + b*64 + j], 1.0f);
        const float sv = ao * rsqrtf(bo);
        sl[idx] = sv;
        out[96 + idx] = sv;
    }
    __syncthreads();
    if (tid < 32) {
        float p = bout[0];
        for (int j = 0; j < 64; ++j) p = fmaf(sl[tid*64 + j], Wout[j], p);
        out[tid] = sigf(p);
    } else if (tid < 96) {
        out[32 + (tid - 32)] = ((tid - 32) & 1) ? 1.0f : 0.0f;
    }
}

// ---------------------------------------------------------------------------
extern "C" void kernel_launch(void* const* d_in, const int* in_sizes, int n_in,
                              void* d_out, int out_size, void* d_ws, size_t ws_size,
                              hipStream_t stream)
{
    (void)in_sizes; (void)n_in; (void)out_size;
    const int*   tok   = (const int*)  d_in[0];
    const float* emb   = (const float*)d_in[1];
    const float* st_tr = (const float*)d_in[2];
    const float* st_ac = (const float*)d_in[3];
    const float* dec_a = (const float*)d_in[4];
    const float* dec_o = (const float*)d_in[5];
    const int*   ial   = (const int*)  d_in[6];
    const int*   iar   = (const int*)  d_in[7];
    const int*   iol   = (const int*)  d_in[8];
    const int*   ior   = (const int*)  d_in[9];
    const float* Wq    = (const float*)d_in[10];
    const float* bq    = (const float*)d_in[11];
    const float* Win   = (const float*)d_in[12];
    const float* b_in  = (const float*)d_in[13];
    const float* Wao   = (const float*)d_in[14];
    const float* bao   = (const float*)d_in[15];
    const float* Wsyn  = (const float*)d_in[16];
    const float* bsyn  = (const float*)d_in[17];
    const float* ln_g  = (const float*)d_in[18];
    const float* ln_b  = (const float*)d_in[19];
    const float* W1    = (const float*)d_in[20];
    const float* b1    = (const float*)d_in[21];
    const float* W2    = (const float*)d_in[22];
    const float* b2    = (const float*)d_in[23];
    const float* Wout  = (const float*)d_in[24];
    const float* bout  = (const float*)d_in[25];
    float* out = (float*)d_out;
    char* wsb = (char*)d_ws;
    if (ws_size < (size_t)66715904) return;
    unsigned short* khb   = (unsigned short*)(wsb + 0);          // 16 MB
    unsigned short* vhb   = (unsigned short*)(wsb + 16777216);   // 16 MB
    unsigned short* Wsb   = (unsigned short*)(wsb + 33554432);   // 16 MB
    unsigned short* W1t   = (unsigned short*)(wsb + 50331648);   // 8 MB
    unsigned short* Wfusb = (unsigned short*)(wsb + 58720256);   // 4 MB
    unsigned short* W2t   = (unsigned short*)(wsb + 62914560);   // 512 KB
    float* trace = (float*)(wsb + 63438848);   // 2.5 MB
    float* actb  = (float*)(wsb + 66060288);   // 256 KB
    float* sg    = (float*)(wsb + 66322432);   // 256 KB
    float* attnh = (float*)(wsb + 66584576);   // 64 KB
    float* aaB   = (float*)(wsb + 66650112);
    float* baB   = (float*)(wsb + 66658304);
    float* aoB   = (float*)(wsb + 66666496);
    float* boB   = (float*)(wsb + 66682880);
    float* bs2   = (float*)(wsb + 66699264);
    float* stats = (float*)(wsb + 66715648);

    k0_init<<<dim3(2841), dim3(256), 0, stream>>>(st_tr, st_ac, iol, ior,
        trace, actb, aaB, baB, aoB, boB, stats);
    s1_kv_mfma<<<dim3(1024), dim3(256), 0, stream>>>(tok, emb, Win, b_in, khb, vhb);
    s2_wfused<<<dim3(512), dim3(256), 0, stream>>>(Wsyn, Wao, Wfusb);
    s3_bias<<<dim3(16), dim3(256), 0, stream>>>(Wsyn, bao, bsyn, bs2);
    s4_convsyn<<<dim3(8192), dim3(256), 0, stream>>>(Wsyn, Wsb);
    s5_convnlm<<<dim3(1024), dim3(256), 0, stream>>>(W1, b1, W2, W1t, W2t);
    for (int u = 0; u < 20; ++u) {
        k1_attn<<<dim3(256), dim3(512), 0, stream>>>(actb, dec_a, dec_o,
            ial, iar, iol, ior, Wq, bq, Win, b_in, khb, vhb,
            aaB, baB, aoB, boB, attnh, stats, u);
        k2b_syn<<<dim3(512), dim3(512), 0, stream>>>(attnh, actb, Wfusb, Wsb,
            bs2, sg, stats);
        k3_nlm<<<dim3(512), dim3(256), 0, stream>>>(sg, stats, ln_g, ln_b,
            W1t, W2t, b2, trace, actb, u);
    }
    k4_final<<<dim3(1), dim3(256), 0, stream>>>(aoB, boB, actb, dec_o,
        iol, ior, Wout, bout, out);
}